// Round 6
// baseline (381.060 us; speedup 1.0000x reference)
//
#include <hip/hip_runtime.h>
#include <math.h>

// Problem constants (fixed by the reference setup)
#define NTOT 32768
#define NB   64
#define NPB  512      // rows per segment
#define DQK  128
#define MF   256      // feature count m
#define DVV  256      // value dim

#define QK_SCALE   0.29730177875068026f   // 128^-0.25
#define INV_SQRT_M 0.0625f                // 1/sqrt(256)
#define EPS_PHI    1e-4f
#define EPS_NORM   1e-8f
#define EPS_ISM    (EPS_PHI * INV_SQRT_M)

static __device__ __forceinline__ float red_max32(float v) {
    v = fmaxf(v, __shfl_xor(v, 1, 64));
    v = fmaxf(v, __shfl_xor(v, 2, 64));
    v = fmaxf(v, __shfl_xor(v, 4, 64));
    v = fmaxf(v, __shfl_xor(v, 8, 64));
    v = fmaxf(v, __shfl_xor(v, 16, 64));
    return v;
}
static __device__ __forceinline__ float red_sum32(float v) {
    v += __shfl_xor(v, 1, 64);
    v += __shfl_xor(v, 2, 64);
    v += __shfl_xor(v, 4, 64);
    v += __shfl_xor(v, 8, 64);
    v += __shfl_xor(v, 16, 64);
    return v;
}

// ---------------------------------------------------------------------------
// Kernel 1: U = (X * d^-1/4) @ omega  [32 rows x all 256 cols per block].
// 1024 blocks -> 4 blocks/CU = 4 waves/SIMD. 256 threads: tx=tid&31 (8 cols),
// ty=tid>>5 (4 rows). 4x8 micro, acc 32 regs. omega chunk double-buffered in
// registers (oreg). A-frag = broadcast scalar LDS reads (measured conflict-
// free). NO min-waves hint: (256,4)/(1024,*) pinned VGPR=64 -> spill (r2-r5).
//   IS_QUERY: out = Qp = (exp(U-h-rowmax)+eps)/sqrt(m); aux = norm
//   else:     out = exp(U-h-rowmax); aux = rowmax
// ---------------------------------------------------------------------------
template <bool IS_QUERY>
__global__ __launch_bounds__(256) void phi_kernel(
    const float* __restrict__ X, const float* __restrict__ omega,
    const float* __restrict__ Ksum,
    float* __restrict__ out, float* __restrict__ aux)
{
    __shared__ __align__(16) float xs[32][132];   // row-major (+4 pad)
    __shared__ __align__(16) float oms[16][256];  // k-major omega chunk
    __shared__ float KsS[256];

    const int tid = threadIdx.x;
    const int tx  = tid & 31;
    const int ty  = tid >> 5;                     // 0..7
    const int row0 = blockIdx.x * 32;

    if (IS_QUERY) KsS[tid] = Ksum[(row0 >> 9) * MF + tid];

    // ---- stage X tile (32x128), scaled, row-major ----
    {
        const float4* Xv = (const float4*)(X + (size_t)row0 * DQK);
        #pragma unroll
        for (int j = 0; j < 4; ++j) {
            int idx = tid + 256 * j;
            int r = idx >> 5, c4 = idx & 31;
            float4 v = Xv[idx];
            v.x *= QK_SCALE; v.y *= QK_SCALE; v.z *= QK_SCALE; v.w *= QK_SCALE;
            *(float4*)&xs[r][c4 * 4] = v;
        }
    }

    float acc[4][8] = {};
    float h[4] = {};

    const float4* Ov = (const float4*)omega;
    float4 oreg[4];
    #pragma unroll
    for (int j = 0; j < 4; ++j) oreg[j] = Ov[tid + 256 * j];

    for (int c = 0; c < 8; ++c) {
        __syncthreads();
        #pragma unroll
        for (int j = 0; j < 4; ++j) {
            int idx = tid + 256 * j;
            *(float4*)&oms[idx >> 6][(idx & 63) * 4] = oreg[j];
        }
        __syncthreads();
        if (c < 7) {
            #pragma unroll
            for (int j = 0; j < 4; ++j)
                oreg[j] = Ov[(c + 1) * 1024 + tid + 256 * j];
        }
        const int kc = c * 16;
        #pragma unroll 4
        for (int kk = 0; kk < 16; ++kk) {
            float4 b0 = *(const float4*)&oms[kk][tx * 4];
            float4 b1 = *(const float4*)&oms[kk][128 + tx * 4];
            float bv[8] = {b0.x, b0.y, b0.z, b0.w, b1.x, b1.y, b1.z, b1.w};
            #pragma unroll
            for (int i = 0; i < 4; ++i) {
                const float av = xs[ty * 4 + i][kc + kk];   // broadcast read
                h[i] = fmaf(av, av, h[i]);
                #pragma unroll
                for (int j = 0; j < 8; ++j)
                    acc[i][j] = fmaf(av, bv[j], acc[i][j]);
            }
        }
    }

    // ---- epilogue (acc cols j<4 -> tx*4+j, j>=4 -> 128+tx*4+j-4) ----
    #pragma unroll
    for (int i = 0; i < 4; ++i) {
        const int grow = row0 + ty * 4 + i;
        float mx = acc[i][0];
        #pragma unroll
        for (int j = 1; j < 8; ++j) mx = fmaxf(mx, acc[i][j]);
        mx = red_max32(mx);
        const float hm = 0.5f * h[i] + mx;

        if (IS_QUERY) {
            float q[8];
            #pragma unroll
            for (int j = 0; j < 8; ++j)
                q[j] = (__expf(acc[i][j] - hm) + EPS_PHI) * INV_SQRT_M;
            float4 o0 = {q[0], q[1], q[2], q[3]};
            float4 o1 = {q[4], q[5], q[6], q[7]};
            *(float4*)&out[(size_t)grow * MF + tx * 4]       = o0;
            *(float4*)&out[(size_t)grow * MF + 128 + tx * 4] = o1;
            float np = 0.f;
            #pragma unroll
            for (int j = 0; j < 4; ++j) np = fmaf(q[j], KsS[tx * 4 + j], np);
            #pragma unroll
            for (int j = 0; j < 4; ++j) np = fmaf(q[4 + j], KsS[128 + tx * 4 + j], np);
            np = red_sum32(np);
            if (tx == 0) aux[grow] = np;
        } else {
            float4 o0 = {__expf(acc[i][0] - hm), __expf(acc[i][1] - hm),
                         __expf(acc[i][2] - hm), __expf(acc[i][3] - hm)};
            float4 o1 = {__expf(acc[i][4] - hm), __expf(acc[i][5] - hm),
                         __expf(acc[i][6] - hm), __expf(acc[i][7] - hm)};
            *(float4*)&out[(size_t)grow * MF + tx * 4]       = o0;
            *(float4*)&out[(size_t)grow * MF + 128 + tx * 4] = o1;
            if (tx == 0) aux[grow] = mx;
        }
    }
}

// ---------------------------------------------------------------------------
// Kernel 2: sexp[n] = exp(rmax[n] - max_{segment} rmax)
// ---------------------------------------------------------------------------
__global__ __launch_bounds__(256) void segsexp_kernel(
    const float* __restrict__ rmax, float* __restrict__ sexp)
{
    const int b = blockIdx.x, tid = threadIdx.x;
    const float r0 = rmax[b * NPB + tid];
    const float r1 = rmax[b * NPB + 256 + tid];
    float v = fmaxf(r0, r1);
    v = red_max32(v);
    v = fmaxf(v, __shfl_xor(v, 32, 64));
    __shared__ float red[4];
    if ((tid & 63) == 0) red[tid >> 6] = v;
    __syncthreads();
    const float smax = fmaxf(fmaxf(red[0], red[1]), fmaxf(red[2], red[3]));
    sexp[b * NPB + tid]       = __expf(r0 - smax);
    sexp[b * NPB + 256 + tid] = __expf(r1 - smax);
}

// ---------------------------------------------------------------------------
// Kernel 3: KV partial = Kp_chunk^T @ V_chunk over 256 rows (2-way n-split,
// 512 blocks). 256 threads, 8x8 micro + register prefetch (areg/vreg/esreg).
// Kp = fmaf(A', sexp[n]/sqrt(m), eps') with A' = exp(U-h-rmax) from phi_K.
// ch==0 -> KV/Ksum; ch==1 -> partials (KVp = idle Qp buffer). No atomics.
// Plain __launch_bounds__(256): ~126 VGPR, no spill.
// ---------------------------------------------------------------------------
__global__ __launch_bounds__(256) void kv_kernel(
    const float* __restrict__ A, const float* __restrict__ V,
    const float* __restrict__ sexp,
    float* __restrict__ KV, float* __restrict__ KVp,
    float* __restrict__ Ksum, float* __restrict__ KsumP)
{
    __shared__ __align__(16) float Kps[32][128];
    __shared__ __align__(16) float Vs[32][128];

    const int tid = threadIdx.x;
    const int tx = tid & 15, ty = tid >> 4;
    const int vt = blockIdx.x, mt = blockIdx.y;
    const int b  = blockIdx.z >> 1, ch = blockIdx.z & 1;
    const int m0 = mt * 128, v0 = vt * 128;
    const size_t n0 = (size_t)b * NPB + ch * 256;

    const int ln  = tid >> 5;     // 0..7  (n within chunk, +8j)
    const int lm4 = tid & 31;     // float4 column

    float acc[8][8] = {};
    float4 ks4 = {0.f, 0.f, 0.f, 0.f};

    float4 areg[4], vreg[4];
    float  esr[4];
    #pragma unroll
    for (int j = 0; j < 4; ++j) {
        const size_t n = n0 + ln + 8 * j;
        areg[j] = *(const float4*)&A[n * MF + m0 + lm4 * 4];
        vreg[j] = *(const float4*)&V[n * DVV + v0 + lm4 * 4];
        esr[j]  = sexp[n];
    }

    for (int c = 0; c < 8; ++c) {
        __syncthreads();
        #pragma unroll
        for (int j = 0; j < 4; ++j) {
            const float s2 = esr[j] * INV_SQRT_M;
            float4 e;
            e.x = fmaf(areg[j].x, s2, EPS_ISM);
            e.y = fmaf(areg[j].y, s2, EPS_ISM);
            e.z = fmaf(areg[j].z, s2, EPS_ISM);
            e.w = fmaf(areg[j].w, s2, EPS_ISM);
            ks4.x += e.x; ks4.y += e.y; ks4.z += e.z; ks4.w += e.w;
            *(float4*)&Kps[ln + 8 * j][lm4 * 4] = e;
            *(float4*)&Vs [ln + 8 * j][lm4 * 4] = vreg[j];
        }
        __syncthreads();
        if (c < 7) {
            #pragma unroll
            for (int j = 0; j < 4; ++j) {
                const size_t n = n0 + (c + 1) * 32 + ln + 8 * j;
                areg[j] = *(const float4*)&A[n * MF + m0 + lm4 * 4];
                vreg[j] = *(const float4*)&V[n * DVV + v0 + lm4 * 4];
                esr[j]  = sexp[n];
            }
        }
        #pragma unroll 8
        for (int kk = 0; kk < 32; ++kk) {
            float4 b0 = *(const float4*)&Vs[kk][tx * 4];
            float4 b1 = *(const float4*)&Vs[kk][64 + tx * 4];
            float bv[8] = {b0.x, b0.y, b0.z, b0.w, b1.x, b1.y, b1.z, b1.w};
            #pragma unroll
            for (int i = 0; i < 8; ++i) {
                const float av = Kps[kk][ty * 8 + i];   // broadcast read
                #pragma unroll
                for (int j = 0; j < 8; ++j)
                    acc[i][j] = fmaf(av, bv[j], acc[i][j]);
            }
        }
    }

    float* __restrict__ dKV = ch ? KVp : KV;
    #pragma unroll
    for (int i = 0; i < 8; ++i) {
        const size_t base = ((size_t)b * MF + m0 + ty * 8 + i) * DVV + v0;
        float4 o0 = {acc[i][0], acc[i][1], acc[i][2], acc[i][3]};
        float4 o1 = {acc[i][4], acc[i][5], acc[i][6], acc[i][7]};
        *(float4*)&dKV[base + tx * 4]      = o0;
        *(float4*)&dKV[base + 64 + tx * 4] = o1;
    }

    if (vt == 0) {
        __syncthreads();                       // compute reads of Kps done
        *(float4*)&Kps[ln][lm4 * 4] = ks4;     // scratch [8][128]
        __syncthreads();
        if (tid < 128) {
            float s = 0.f;
            #pragma unroll
            for (int g = 0; g < 8; ++g) s += Kps[g][tid];
            (ch ? KsumP : Ksum)[b * MF + m0 + tid] = s;
        }
    }
}

// ---------------------------------------------------------------------------
// Kernel 3b: fold the ch==1 partials into KV / Ksum.
// ---------------------------------------------------------------------------
__global__ __launch_bounds__(256) void kvreduce_kernel(
    float* __restrict__ KV, const float* __restrict__ KVp,
    float* __restrict__ Ksum, const float* __restrict__ KsumP)
{
    const int idx = blockIdx.x * 256 + threadIdx.x;
    const int stride = gridDim.x * 256;
    const int TOT4 = NB * MF * DVV / 4;
    for (int i = idx; i < TOT4; i += stride) {
        float4 a = ((const float4*)KV)[i];
        float4 p = ((const float4*)KVp)[i];
        a.x += p.x; a.y += p.y; a.z += p.z; a.w += p.w;
        ((float4*)KV)[i] = a;
    }
    const int KS4 = NB * MF / 4;
    for (int i = idx; i < KS4; i += stride) {
        float4 a = ((const float4*)Ksum)[i];
        float4 p = ((const float4*)KsumP)[i];
        a.x += p.x; a.y += p.y; a.z += p.z; a.w += p.w;
        ((float4*)Ksum)[i] = a;
    }
}

// ---------------------------------------------------------------------------
// Kernel 4: out = (Qp @ KV[b]) / (norm + eps). 64 rows x 128 v per block ->
// grid (2,8,64)=1024 blocks = 4 blocks/CU = 4 waves/SIMD (r5 showed 512-block
// version stuck at 19% occupancy). 4x8 micro + register prefetch. A-frag =
// broadcast scalar reads; B-frag cols split (tx*4, 64+tx*4).
// ---------------------------------------------------------------------------
__global__ __launch_bounds__(256) void out_kernel(
    const float* __restrict__ Qp, const float* __restrict__ KVm,
    const float* __restrict__ normv, float* __restrict__ out)
{
    __shared__ __align__(16) float Qs[64][36];    // row-major (+4 pad)
    __shared__ __align__(16) float KVs[32][128];  // k-major
    __shared__ float nrmS[64];

    const int tid = threadIdx.x;
    const int tx = tid & 15, ty = tid >> 4;       // ty 0..15 -> 4 rows each
    const int vt = blockIdx.x, rt = blockIdx.y, b = blockIdx.z;
    const int v0 = vt * 128;
    const int r0 = b * NPB + rt * 64;

    if (tid < 64) nrmS[tid] = normv[r0 + tid];

    const int qr  = tid >> 3;     // 0..31 (+32)
    const int qm4 = tid & 7;
    const int km  = tid >> 5;     // 0..7  (+8j)
    const int kv4 = tid & 31;

    float acc[4][8] = {};

    float4 qreg[2], kreg[4];
    #pragma unroll
    for (int j = 0; j < 2; ++j)
        qreg[j] = *(const float4*)&Qp[(size_t)(r0 + qr + 32 * j) * MF + qm4 * 4];
    #pragma unroll
    for (int j = 0; j < 4; ++j)
        kreg[j] = *(const float4*)&KVm[((size_t)b * MF + km + 8 * j) * DVV + v0 + kv4 * 4];

    for (int c = 0; c < 8; ++c) {
        __syncthreads();
        #pragma unroll
        for (int j = 0; j < 2; ++j)
            *(float4*)&Qs[qr + 32 * j][qm4 * 4] = qreg[j];
        #pragma unroll
        for (int j = 0; j < 4; ++j)
            *(float4*)&KVs[km + 8 * j][kv4 * 4] = kreg[j];
        __syncthreads();
        if (c < 7) {
            const int mc = (c + 1) * 32;
            #pragma unroll
            for (int j = 0; j < 2; ++j)
                qreg[j] = *(const float4*)&Qp[(size_t)(r0 + qr + 32 * j) * MF + mc + qm4 * 4];
            #pragma unroll
            for (int j = 0; j < 4; ++j)
                kreg[j] = *(const float4*)&KVm[((size_t)b * MF + mc + km + 8 * j) * DVV + v0 + kv4 * 4];
        }
        #pragma unroll 4
        for (int kk = 0; kk < 32; ++kk) {
            float4 b0 = *(const float4*)&KVs[kk][tx * 4];
            float4 b1 = *(const float4*)&KVs[kk][64 + tx * 4];
            float bv[8] = {b0.x, b0.y, b0.z, b0.w, b1.x, b1.y, b1.z, b1.w};
            #pragma unroll
            for (int i = 0; i < 4; ++i) {
                const float av = Qs[ty * 4 + i][kk];    // broadcast read
                #pragma unroll
                for (int j = 0; j < 8; ++j)
                    acc[i][j] = fmaf(av, bv[j], acc[i][j]);
            }
        }
    }

    #pragma unroll
    for (int i = 0; i < 4; ++i) {
        const int row = ty * 4 + i;
        const float inv = 1.0f / (nrmS[row] + EPS_NORM);
        float4 o0 = {acc[i][0] * inv, acc[i][1] * inv, acc[i][2] * inv, acc[i][3] * inv};
        float4 o1 = {acc[i][4] * inv, acc[i][5] * inv, acc[i][6] * inv, acc[i][7] * inv};
        const size_t base = (size_t)(r0 + row) * DVV + v0;
        *(float4*)&out[base + tx * 4]      = o0;
        *(float4*)&out[base + 64 + tx * 4] = o1;
    }
}

// ---------------------------------------------------------------------------
extern "C" void kernel_launch(void* const* d_in, const int* in_sizes, int n_in,
                              void* d_out, int out_size, void* d_ws, size_t ws_size,
                              hipStream_t stream)
{
    const float* Q     = (const float*)d_in[0];
    const float* K     = (const float*)d_in[1];
    const float* V     = (const float*)d_in[2];
    const float* omega = (const float*)d_in[3];
    float* out = (float*)d_out;

    float* ws    = (float*)d_ws;
    float* Qp    = ws;                              // N*M  (doubles as KVp scratch during kv)
    float* A     = Qp    + (size_t)NTOT * MF;       // N*M   A' = exp(U-h-rmax)
    float* KV    = A     + (size_t)NTOT * MF;       // B*M*DV
    float* Ksum  = KV    + (size_t)NB * MF * DVV;   // B*M
    float* KsumP = Ksum  + (size_t)NB * MF;         // B*M
    float* rmaxA = KsumP + (size_t)NB * MF;         // N
    float* sexp  = rmaxA + NTOT;                    // N
    float* normv = sexp  + NTOT;                    // N

    phi_kernel<false><<<NTOT / 32, 256, 0, stream>>>(K, omega, (const float*)nullptr, A, rmaxA);
    segsexp_kernel<<<NB, 256, 0, stream>>>(rmaxA, sexp);
    kv_kernel<<<dim3(2, 2, NB * 2), 256, 0, stream>>>(A, V, sexp, KV, Qp, Ksum, KsumP);
    kvreduce_kernel<<<2048, 256, 0, stream>>>(KV, Qp, Ksum, KsumP);
    phi_kernel<true ><<<NTOT / 32, 256, 0, stream>>>(Q, omega, Ksum, Qp, normv);
    out_kernel<<<dim3(2, 8, NB), 256, 0, stream>>>(Qp, KV, normv, out);
}

// Round 7
// 348.513 us; speedup vs baseline: 1.0934x; 1.0934x over previous
//
#include <hip/hip_runtime.h>
#include <math.h>

// Problem constants (fixed by the reference setup)
#define NTOT 32768
#define NB   64
#define NPB  512      // rows per segment
#define DQK  128
#define MF   256      // feature count m
#define DVV  256      // value dim

#define QK_SCALE   0.29730177875068026f   // 128^-0.25
#define INV_SQRT_M 0.0625f                // 1/sqrt(256)
#define EPS_PHI    1e-4f
#define EPS_NORM   1e-8f
#define EPS_ISM    (EPS_PHI * INV_SQRT_M)

static __device__ __forceinline__ float red_max32(float v) {
    v = fmaxf(v, __shfl_xor(v, 1, 64));
    v = fmaxf(v, __shfl_xor(v, 2, 64));
    v = fmaxf(v, __shfl_xor(v, 4, 64));
    v = fmaxf(v, __shfl_xor(v, 8, 64));
    v = fmaxf(v, __shfl_xor(v, 16, 64));
    return v;
}
static __device__ __forceinline__ float red_sum32(float v) {
    v += __shfl_xor(v, 1, 64);
    v += __shfl_xor(v, 2, 64);
    v += __shfl_xor(v, 4, 64);
    v += __shfl_xor(v, 8, 64);
    v += __shfl_xor(v, 16, 64);
    return v;
}

// ---------------------------------------------------------------------------
// Kernel 1: U = (X * d^-1/4) @ omega  [64 rows x all 256 cols per block].
// 512 blocks = 2 blocks/CU = 8 waves/CU. 8x8 micro (acc 64), omega chunk
// register-prefetched (oreg). A-frag = broadcast scalar LDS reads; B-frag
// cols split (tx*4, 128+tx*4) — both measured conflict-free (r4-r6).
// __launch_bounds__(256, 2): empirical VGPR cap law (w -> 256/w) gives 128;
// kernel needs ~105 live -> NO spill (w=4 capped at 64 and spilled, r2-r6).
//   IS_QUERY: out = Qp = (exp(U-h-rowmax)+eps)/sqrt(m); aux = norm
//   else:     out = exp(U-h-rowmax); aux = rowmax
// ---------------------------------------------------------------------------
template <bool IS_QUERY>
__global__ __launch_bounds__(256, 2) void phi_kernel(
    const float* __restrict__ X, const float* __restrict__ omega,
    const float* __restrict__ Ksum,
    float* __restrict__ out, float* __restrict__ aux)
{
    __shared__ __align__(16) float xs[64][132];   // row-major (+4 pad)
    __shared__ __align__(16) float oms[16][256];  // k-major omega chunk
    __shared__ float KsS[256];

    const int tid = threadIdx.x;
    const int tx  = tid & 31;
    const int ty  = tid >> 5;
    const int row0 = blockIdx.x * 64;

    if (IS_QUERY) KsS[tid] = Ksum[(row0 >> 9) * MF + tid];

    // ---- stage X tile (64x128), scaled, row-major ----
    {
        const float4* Xv = (const float4*)(X + (size_t)row0 * DQK);
        #pragma unroll
        for (int j = 0; j < 8; ++j) {
            int idx = tid + 256 * j;
            int r = idx >> 5, c4 = idx & 31;
            float4 v = Xv[idx];
            v.x *= QK_SCALE; v.y *= QK_SCALE; v.z *= QK_SCALE; v.w *= QK_SCALE;
            *(float4*)&xs[r][c4 * 4] = v;
        }
    }

    float acc[8][8] = {};
    float h[8] = {};

    const float4* Ov = (const float4*)omega;
    float4 oreg[4];
    #pragma unroll
    for (int j = 0; j < 4; ++j) oreg[j] = Ov[tid + 256 * j];

    for (int c = 0; c < 8; ++c) {
        __syncthreads();
        #pragma unroll
        for (int j = 0; j < 4; ++j) {
            int idx = tid + 256 * j;
            *(float4*)&oms[idx >> 6][(idx & 63) * 4] = oreg[j];
        }
        __syncthreads();
        if (c < 7) {
            #pragma unroll
            for (int j = 0; j < 4; ++j)
                oreg[j] = Ov[(c + 1) * 1024 + tid + 256 * j];
        }
        const int kc = c * 16;
        #pragma unroll 4
        for (int kk = 0; kk < 16; ++kk) {
            float4 b0 = *(const float4*)&oms[kk][tx * 4];
            float4 b1 = *(const float4*)&oms[kk][128 + tx * 4];
            float bv[8] = {b0.x, b0.y, b0.z, b0.w, b1.x, b1.y, b1.z, b1.w};
            #pragma unroll
            for (int i = 0; i < 8; ++i) {
                const float av = xs[ty * 8 + i][kc + kk];   // broadcast read
                h[i] = fmaf(av, av, h[i]);
                #pragma unroll
                for (int j = 0; j < 8; ++j)
                    acc[i][j] = fmaf(av, bv[j], acc[i][j]);
            }
        }
    }

    // ---- epilogue (acc cols j<4 -> tx*4+j, j>=4 -> 128+tx*4+j-4) ----
    #pragma unroll
    for (int i = 0; i < 8; ++i) {
        const int grow = row0 + ty * 8 + i;
        float mx = acc[i][0];
        #pragma unroll
        for (int j = 1; j < 8; ++j) mx = fmaxf(mx, acc[i][j]);
        mx = red_max32(mx);
        const float hm = 0.5f * h[i] + mx;

        if (IS_QUERY) {
            float q[8];
            #pragma unroll
            for (int j = 0; j < 8; ++j)
                q[j] = (__expf(acc[i][j] - hm) + EPS_PHI) * INV_SQRT_M;
            float4 o0 = {q[0], q[1], q[2], q[3]};
            float4 o1 = {q[4], q[5], q[6], q[7]};
            *(float4*)&out[(size_t)grow * MF + tx * 4]       = o0;
            *(float4*)&out[(size_t)grow * MF + 128 + tx * 4] = o1;
            float np = 0.f;
            #pragma unroll
            for (int j = 0; j < 4; ++j) np = fmaf(q[j], KsS[tx * 4 + j], np);
            #pragma unroll
            for (int j = 0; j < 4; ++j) np = fmaf(q[4 + j], KsS[128 + tx * 4 + j], np);
            np = red_sum32(np);
            if (tx == 0) aux[grow] = np;
        } else {
            float4 o0 = {__expf(acc[i][0] - hm), __expf(acc[i][1] - hm),
                         __expf(acc[i][2] - hm), __expf(acc[i][3] - hm)};
            float4 o1 = {__expf(acc[i][4] - hm), __expf(acc[i][5] - hm),
                         __expf(acc[i][6] - hm), __expf(acc[i][7] - hm)};
            *(float4*)&out[(size_t)grow * MF + tx * 4]       = o0;
            *(float4*)&out[(size_t)grow * MF + 128 + tx * 4] = o1;
            if (tx == 0) aux[grow] = mx;
        }
    }
}

// ---------------------------------------------------------------------------
// Kernel 2: sexp[n] = exp(rmax[n] - max_{segment} rmax)
// ---------------------------------------------------------------------------
__global__ __launch_bounds__(256) void segsexp_kernel(
    const float* __restrict__ rmax, float* __restrict__ sexp)
{
    const int b = blockIdx.x, tid = threadIdx.x;
    const float r0 = rmax[b * NPB + tid];
    const float r1 = rmax[b * NPB + 256 + tid];
    float v = fmaxf(r0, r1);
    v = red_max32(v);
    v = fmaxf(v, __shfl_xor(v, 32, 64));
    __shared__ float red[4];
    if ((tid & 63) == 0) red[tid >> 6] = v;
    __syncthreads();
    const float smax = fmaxf(fmaxf(red[0], red[1]), fmaxf(red[2], red[3]));
    sexp[b * NPB + tid]       = __expf(r0 - smax);
    sexp[b * NPB + 256 + tid] = __expf(r1 - smax);
}

// ---------------------------------------------------------------------------
// Kernel 3: KV partial = Kp_chunk^T @ V_chunk over 128 rows. 4-way n-split ->
// grid (2,2,256) = 1024 blocks = 4 blocks/CU = 4 waves/SIMD (LDS 32 KB).
// 256 threads, 8x8 micro + register prefetch (areg/vreg/esr), (256,2) ->
// ~115 VGPR, no spill. Kp = fmaf(A', sexp[n]/sqrt(m), eps'). Partials go to
// dead buffers with NO atomics: ch0->KV, ch1/ch2->Qp (idle until phi_Q),
// ch3->d_out (idle until out_kernel); folded by kvreduce_kernel.
// ---------------------------------------------------------------------------
__global__ __launch_bounds__(256, 2) void kv_kernel(
    const float* __restrict__ A, const float* __restrict__ V,
    const float* __restrict__ sexp,
    float* __restrict__ KV, float* __restrict__ P1,
    float* __restrict__ P2, float* __restrict__ P3,
    float* __restrict__ Ksum, float* __restrict__ KsumP)
{
    __shared__ __align__(16) float Kps[32][128];
    __shared__ __align__(16) float Vs[32][128];

    const int tid = threadIdx.x;
    const int tx = tid & 15, ty = tid >> 4;
    const int vt = blockIdx.x, mt = blockIdx.y;
    const int b  = blockIdx.z >> 2, ch = blockIdx.z & 3;
    const int m0 = mt * 128, v0 = vt * 128;
    const size_t n0 = (size_t)b * NPB + ch * 128;

    const int ln  = tid >> 5;     // 0..7  (n within chunk, +8j)
    const int lm4 = tid & 31;     // float4 column

    float acc[8][8] = {};
    float4 ks4 = {0.f, 0.f, 0.f, 0.f};

    float4 areg[4], vreg[4];
    float  esr[4];
    #pragma unroll
    for (int j = 0; j < 4; ++j) {
        const size_t n = n0 + ln + 8 * j;
        areg[j] = *(const float4*)&A[n * MF + m0 + lm4 * 4];
        vreg[j] = *(const float4*)&V[n * DVV + v0 + lm4 * 4];
        esr[j]  = sexp[n];
    }

    for (int c = 0; c < 4; ++c) {
        __syncthreads();
        #pragma unroll
        for (int j = 0; j < 4; ++j) {
            const float s2 = esr[j] * INV_SQRT_M;
            float4 e;
            e.x = fmaf(areg[j].x, s2, EPS_ISM);
            e.y = fmaf(areg[j].y, s2, EPS_ISM);
            e.z = fmaf(areg[j].z, s2, EPS_ISM);
            e.w = fmaf(areg[j].w, s2, EPS_ISM);
            ks4.x += e.x; ks4.y += e.y; ks4.z += e.z; ks4.w += e.w;
            *(float4*)&Kps[ln + 8 * j][lm4 * 4] = e;
            *(float4*)&Vs [ln + 8 * j][lm4 * 4] = vreg[j];
        }
        __syncthreads();
        if (c < 3) {
            #pragma unroll
            for (int j = 0; j < 4; ++j) {
                const size_t n = n0 + (c + 1) * 32 + ln + 8 * j;
                areg[j] = *(const float4*)&A[n * MF + m0 + lm4 * 4];
                vreg[j] = *(const float4*)&V[n * DVV + v0 + lm4 * 4];
                esr[j]  = sexp[n];
            }
        }
        #pragma unroll 8
        for (int kk = 0; kk < 32; ++kk) {
            float4 b0 = *(const float4*)&Vs[kk][tx * 4];
            float4 b1 = *(const float4*)&Vs[kk][64 + tx * 4];
            float bv[8] = {b0.x, b0.y, b0.z, b0.w, b1.x, b1.y, b1.z, b1.w};
            #pragma unroll
            for (int i = 0; i < 8; ++i) {
                const float av = Kps[kk][ty * 8 + i];   // broadcast read
                #pragma unroll
                for (int j = 0; j < 8; ++j)
                    acc[i][j] = fmaf(av, bv[j], acc[i][j]);
            }
        }
    }

    float* __restrict__ dKV = (ch == 0) ? KV : (ch == 1) ? P1 : (ch == 2) ? P2 : P3;
    #pragma unroll
    for (int i = 0; i < 8; ++i) {
        const size_t base = ((size_t)b * MF + m0 + ty * 8 + i) * DVV + v0;
        float4 o0 = {acc[i][0], acc[i][1], acc[i][2], acc[i][3]};
        float4 o1 = {acc[i][4], acc[i][5], acc[i][6], acc[i][7]};
        *(float4*)&dKV[base + tx * 4]      = o0;
        *(float4*)&dKV[base + 64 + tx * 4] = o1;
    }

    if (vt == 0) {
        __syncthreads();                       // compute reads of Kps done
        *(float4*)&Kps[ln][lm4 * 4] = ks4;     // scratch [8][128]
        __syncthreads();
        if (tid < 128) {
            float s = 0.f;
            #pragma unroll
            for (int g = 0; g < 8; ++g) s += Kps[g][tid];
            float* dst = (ch == 0) ? (Ksum + b * MF)
                                   : (KsumP + ((ch - 1) * NB + b) * MF);
            dst[m0 + tid] = s;
        }
    }
}

// ---------------------------------------------------------------------------
// Kernel 3b: fold the three partial buffers into KV / Ksum.
// ---------------------------------------------------------------------------
__global__ __launch_bounds__(256) void kvreduce_kernel(
    float* __restrict__ KV, const float* __restrict__ P1,
    const float* __restrict__ P2, const float* __restrict__ P3,
    float* __restrict__ Ksum, const float* __restrict__ KsumP)
{
    const int idx = blockIdx.x * 256 + threadIdx.x;
    const int stride = gridDim.x * 256;
    const int TOT4 = NB * MF * DVV / 4;
    for (int i = idx; i < TOT4; i += stride) {
        float4 a  = ((const float4*)KV)[i];
        float4 p1 = ((const float4*)P1)[i];
        float4 p2 = ((const float4*)P2)[i];
        float4 p3 = ((const float4*)P3)[i];
        a.x += p1.x + p2.x + p3.x;
        a.y += p1.y + p2.y + p3.y;
        a.z += p1.z + p2.z + p3.z;
        a.w += p1.w + p2.w + p3.w;
        ((float4*)KV)[i] = a;
    }
    const int KS4 = NB * MF / 4;
    for (int i = idx; i < KS4; i += stride) {
        float4 a  = ((const float4*)Ksum)[i];
        float4 p1 = ((const float4*)KsumP)[i];
        float4 p2 = ((const float4*)KsumP)[i + KS4];
        float4 p3 = ((const float4*)KsumP)[i + 2 * KS4];
        a.x += p1.x + p2.x + p3.x;
        a.y += p1.y + p2.y + p3.y;
        a.z += p1.z + p2.z + p3.z;
        a.w += p1.w + p2.w + p3.w;
        ((float4*)Ksum)[i] = a;
    }
}

// ---------------------------------------------------------------------------
// Kernel 4: out = (Qp @ KV[b]) / (norm + eps). 128 rows x 128 v per block,
// grid (2,4,64) = 512 = 2 blocks/CU = 8 waves/CU. 8x8 micro + register
// prefetch, (256,2) -> ~110 VGPR, no spill. A-frag rows split (ty*4,
// 64+ty*4) broadcast reads; B-frag cols split (tx*4, 64+tx*4).
// ---------------------------------------------------------------------------
__global__ __launch_bounds__(256, 2) void out_kernel(
    const float* __restrict__ Qp, const float* __restrict__ KVm,
    const float* __restrict__ normv, float* __restrict__ out)
{
    __shared__ __align__(16) float Qs[128][36];   // row-major (+4 pad)
    __shared__ __align__(16) float KVs[32][128];  // k-major
    __shared__ float nrmS[128];

    const int tid = threadIdx.x;
    const int tx = tid & 15, ty = tid >> 4;
    const int vt = blockIdx.x, rt = blockIdx.y, b = blockIdx.z;
    const int v0 = vt * 128;
    const int r0 = b * NPB + rt * 128;

    if (tid < 128) nrmS[tid] = normv[r0 + tid];

    const int qr  = tid >> 3;     // 0..31 (+32j)
    const int qm4 = tid & 7;
    const int km  = tid >> 5;     // 0..7  (+8j)
    const int kv4 = tid & 31;

    float acc[8][8] = {};

    float4 qreg[4], kreg[4];
    #pragma unroll
    for (int j = 0; j < 4; ++j) {
        qreg[j] = *(const float4*)&Qp[(size_t)(r0 + qr + 32 * j) * MF + qm4 * 4];
        kreg[j] = *(const float4*)&KVm[((size_t)b * MF + km + 8 * j) * DVV + v0 + kv4 * 4];
    }

    for (int c = 0; c < 8; ++c) {
        __syncthreads();
        #pragma unroll
        for (int j = 0; j < 4; ++j) {
            *(float4*)&Qs[qr + 32 * j][qm4 * 4]  = qreg[j];
            *(float4*)&KVs[km + 8 * j][kv4 * 4] = kreg[j];
        }
        __syncthreads();
        if (c < 7) {
            const int mc = (c + 1) * 32;
            #pragma unroll
            for (int j = 0; j < 4; ++j) {
                qreg[j] = *(const float4*)&Qp[(size_t)(r0 + qr + 32 * j) * MF + mc + qm4 * 4];
                kreg[j] = *(const float4*)&KVm[((size_t)b * MF + mc + km + 8 * j) * DVV + v0 + kv4 * 4];
            }
        }
        #pragma unroll 4
        for (int kk = 0; kk < 32; ++kk) {
            float4 b0 = *(const float4*)&KVs[kk][tx * 4];
            float4 b1 = *(const float4*)&KVs[kk][64 + tx * 4];
            float bv[8] = {b0.x, b0.y, b0.z, b0.w, b1.x, b1.y, b1.z, b1.w};
            #pragma unroll
            for (int i = 0; i < 8; ++i) {
                const int row = (i < 4) ? (ty * 4 + i) : (64 + ty * 4 + i - 4);
                const float av = Qs[row][kk];           // broadcast read
                #pragma unroll
                for (int j = 0; j < 8; ++j)
                    acc[i][j] = fmaf(av, bv[j], acc[i][j]);
            }
        }
    }

    #pragma unroll
    for (int i = 0; i < 8; ++i) {
        const int row = (i < 4) ? (ty * 4 + i) : (64 + ty * 4 + i - 4);
        const float inv = 1.0f / (nrmS[row] + EPS_NORM);
        float4 o0 = {acc[i][0] * inv, acc[i][1] * inv, acc[i][2] * inv, acc[i][3] * inv};
        float4 o1 = {acc[i][4] * inv, acc[i][5] * inv, acc[i][6] * inv, acc[i][7] * inv};
        const size_t base = (size_t)(r0 + row) * DVV + v0;
        *(float4*)&out[base + tx * 4]      = o0;
        *(float4*)&out[base + 64 + tx * 4] = o1;
    }
}

// ---------------------------------------------------------------------------
extern "C" void kernel_launch(void* const* d_in, const int* in_sizes, int n_in,
                              void* d_out, int out_size, void* d_ws, size_t ws_size,
                              hipStream_t stream)
{
    const float* Q     = (const float*)d_in[0];
    const float* K     = (const float*)d_in[1];
    const float* V     = (const float*)d_in[2];
    const float* omega = (const float*)d_in[3];
    float* out = (float*)d_out;

    float* ws    = (float*)d_ws;
    float* Qp    = ws;                              // N*M  (holds P1,P2 during kv)
    float* A     = Qp    + (size_t)NTOT * MF;       // N*M   A' = exp(U-h-rmax)
    float* KV    = A     + (size_t)NTOT * MF;       // B*M*DV
    float* Ksum  = KV    + (size_t)NB * MF * DVV;   // B*M
    float* KsumP = Ksum  + (size_t)NB * MF;         // 3 * B*M
    float* rmaxA = KsumP + (size_t)3 * NB * MF;     // N
    float* sexp  = rmaxA + NTOT;                    // N
    float* normv = sexp  + NTOT;                    // N

    float* P1 = Qp;                                 // dead until phi_Q
    float* P2 = Qp + (size_t)NB * MF * DVV;
    float* P3 = out;                                // dead until out_kernel

    phi_kernel<false><<<NTOT / 64, 256, 0, stream>>>(K, omega, (const float*)nullptr, A, rmaxA);
    segsexp_kernel<<<NB, 256, 0, stream>>>(rmaxA, sexp);
    kv_kernel<<<dim3(2, 2, NB * 4), 256, 0, stream>>>(A, V, sexp, KV, P1, P2, P3, Ksum, KsumP);
    kvreduce_kernel<<<2048, 256, 0, stream>>>(KV, P1, P2, P3, Ksum, KsumP);
    phi_kernel<true ><<<NTOT / 64, 256, 0, stream>>>(Q, omega, Ksum, Qp, normv);
    out_kernel<<<dim3(2, 4, NB), 256, 0, stream>>>(Qp, KV, normv, out);
}

// Round 8
// 314.243 us; speedup vs baseline: 1.2126x; 1.1091x over previous
//
#include <hip/hip_runtime.h>
#include <math.h>

// Problem constants (fixed by the reference setup)
#define NTOT 32768
#define NB   64
#define NPB  512      // rows per segment
#define DQK  128
#define MF   256      // feature count m
#define DVV  256      // value dim

#define QK_SCALE   0.29730177875068026f   // 128^-0.25
#define INV_SQRT_M 0.0625f                // 1/sqrt(256)
#define EPS_PHI    1e-4f
#define EPS_NORM   1e-8f
#define EPS_ISM    (EPS_PHI * INV_SQRT_M)

static __device__ __forceinline__ float red_max32(float v) {
    v = fmaxf(v, __shfl_xor(v, 1, 64));
    v = fmaxf(v, __shfl_xor(v, 2, 64));
    v = fmaxf(v, __shfl_xor(v, 4, 64));
    v = fmaxf(v, __shfl_xor(v, 8, 64));
    v = fmaxf(v, __shfl_xor(v, 16, 64));
    return v;
}
static __device__ __forceinline__ float red_sum32(float v) {
    v += __shfl_xor(v, 1, 64);
    v += __shfl_xor(v, 2, 64);
    v += __shfl_xor(v, 4, 64);
    v += __shfl_xor(v, 8, 64);
    v += __shfl_xor(v, 16, 64);
    return v;
}

// ---------------------------------------------------------------------------
// Kernel 1: U = (X * d^-1/4) @ omega  [64 rows x all 256 cols per block].
// KEY CHANGE (r8): X tile staged TRANSPOSED (xsT[k][row]) so the A-fragment
// (8 rows, same k) is 8 CONTIGUOUS floats -> 2x ds_read_b128 instead of 8
// scalar reads. No prefetch regs, no a4-hold: live ~ acc64+frag16+h8 ~ 92,
// within the allocator's natural 84-100 choice -> no spill (the r2-r7
// lesson: this compiler never grants >100 VGPR to 256-thr blocks; bodies
// must fit). waves_per_eu(2,8) removes any forced cap (256-reg budget).
//   IS_QUERY: out = Qp = (exp(U-h-rowmax)+eps)/sqrt(m); aux = norm
//   else:     out = exp(U-h-rowmax); aux = rowmax
// ---------------------------------------------------------------------------
template <bool IS_QUERY>
__global__ __launch_bounds__(256) __attribute__((amdgpu_waves_per_eu(2, 8)))
void phi_kernel(
    const float* __restrict__ X, const float* __restrict__ omega,
    const float* __restrict__ Ksum,
    float* __restrict__ out, float* __restrict__ aux)
{
    __shared__ __align__(16) float xsT[128][68];  // transposed: [k][row]; 68 -> row base 16B-aligned
    __shared__ __align__(16) float oms[16][256];  // k-major omega chunk
    __shared__ float KsS[256];

    const int tid = threadIdx.x;
    const int tx  = tid & 31;                     // 8 m-cols: tx*4, 128+tx*4
    const int ty  = tid >> 5;                     // 8 rows:   ty*8 .. ty*8+7
    const int row0 = blockIdx.x * 64;

    if (IS_QUERY) KsS[tid] = Ksum[(row0 >> 9) * MF + tid];

    // ---- stage X tile (64x128), scaled, TRANSPOSED scatter-write ----
    {
        const float4* Xv = (const float4*)(X + (size_t)row0 * DQK);
        #pragma unroll
        for (int j = 0; j < 8; ++j) {
            int idx = tid + 256 * j;
            int r = idx >> 5, c4 = idx & 31;
            float4 v = Xv[idx];
            xsT[c4 * 4 + 0][r] = v.x * QK_SCALE;
            xsT[c4 * 4 + 1][r] = v.y * QK_SCALE;
            xsT[c4 * 4 + 2][r] = v.z * QK_SCALE;
            xsT[c4 * 4 + 3][r] = v.w * QK_SCALE;
        }
    }

    float acc[8][8] = {};
    float h[8] = {};

    const float4* Ov = (const float4*)omega;

    for (int c = 0; c < 8; ++c) {
        __syncthreads();
        #pragma unroll
        for (int j = 0; j < 4; ++j) {
            int idx = tid + 256 * j;
            *(float4*)&oms[idx >> 6][(idx & 63) * 4] = Ov[c * 1024 + idx];
        }
        __syncthreads();
        const int kc = c * 16;
        #pragma unroll 2
        for (int kk = 0; kk < 16; ++kk) {
            float4 a0 = *(const float4*)&xsT[kc + kk][ty * 8];
            float4 a1 = *(const float4*)&xsT[kc + kk][ty * 8 + 4];
            float4 b0 = *(const float4*)&oms[kk][tx * 4];
            float4 b1 = *(const float4*)&oms[kk][128 + tx * 4];
            float av[8] = {a0.x, a0.y, a0.z, a0.w, a1.x, a1.y, a1.z, a1.w};
            float bv[8] = {b0.x, b0.y, b0.z, b0.w, b1.x, b1.y, b1.z, b1.w};
            #pragma unroll
            for (int i = 0; i < 8; ++i) {
                h[i] = fmaf(av[i], av[i], h[i]);
                #pragma unroll
                for (int j = 0; j < 8; ++j)
                    acc[i][j] = fmaf(av[i], bv[j], acc[i][j]);
            }
        }
    }

    // ---- epilogue (acc cols j<4 -> tx*4+j, j>=4 -> 128+tx*4+j-4) ----
    #pragma unroll
    for (int i = 0; i < 8; ++i) {
        const int grow = row0 + ty * 8 + i;
        float mx = acc[i][0];
        #pragma unroll
        for (int j = 1; j < 8; ++j) mx = fmaxf(mx, acc[i][j]);
        mx = red_max32(mx);
        const float hm = 0.5f * h[i] + mx;

        if (IS_QUERY) {
            float q[8];
            #pragma unroll
            for (int j = 0; j < 8; ++j)
                q[j] = (__expf(acc[i][j] - hm) + EPS_PHI) * INV_SQRT_M;
            float4 o0 = {q[0], q[1], q[2], q[3]};
            float4 o1 = {q[4], q[5], q[6], q[7]};
            *(float4*)&out[(size_t)grow * MF + tx * 4]       = o0;
            *(float4*)&out[(size_t)grow * MF + 128 + tx * 4] = o1;
            float np = 0.f;
            #pragma unroll
            for (int j = 0; j < 4; ++j) np = fmaf(q[j], KsS[tx * 4 + j], np);
            #pragma unroll
            for (int j = 0; j < 4; ++j) np = fmaf(q[4 + j], KsS[128 + tx * 4 + j], np);
            np = red_sum32(np);
            if (tx == 0) aux[grow] = np;
        } else {
            float4 o0 = {__expf(acc[i][0] - hm), __expf(acc[i][1] - hm),
                         __expf(acc[i][2] - hm), __expf(acc[i][3] - hm)};
            float4 o1 = {__expf(acc[i][4] - hm), __expf(acc[i][5] - hm),
                         __expf(acc[i][6] - hm), __expf(acc[i][7] - hm)};
            *(float4*)&out[(size_t)grow * MF + tx * 4]       = o0;
            *(float4*)&out[(size_t)grow * MF + 128 + tx * 4] = o1;
            if (tx == 0) aux[grow] = mx;
        }
    }
}

// ---------------------------------------------------------------------------
// Kernel 2: sexp[n] = exp(rmax[n] - max_{segment} rmax)
// ---------------------------------------------------------------------------
__global__ __launch_bounds__(256) void segsexp_kernel(
    const float* __restrict__ rmax, float* __restrict__ sexp)
{
    const int b = blockIdx.x, tid = threadIdx.x;
    const float r0 = rmax[b * NPB + tid];
    const float r1 = rmax[b * NPB + 256 + tid];
    float v = fmaxf(r0, r1);
    v = red_max32(v);
    v = fmaxf(v, __shfl_xor(v, 32, 64));
    __shared__ float red[4];
    if ((tid & 63) == 0) red[tid >> 6] = v;
    __syncthreads();
    const float smax = fmaxf(fmaxf(red[0], red[1]), fmaxf(red[2], red[3]));
    sexp[b * NPB + tid]       = __expf(r0 - smax);
    sexp[b * NPB + 256 + tid] = __expf(r1 - smax);
}

// ---------------------------------------------------------------------------
// Kernel 3: KV partial = Kp_chunk^T @ V_chunk over 128 rows. 4-way n-split ->
// grid (2,2,256) = 1024 blocks = 4 blocks/CU (LDS 32KB). NO prefetch regs
// (live ~ acc64 + staging transients ~ 88 -> no spill); latency hidden by
// 4-block TLP. A-frag Kps[kk][ty*8..+8) is CONTIGUOUS -> 2x b128 reads
// (was 8 scalar broadcasts). Kp = fmaf(A', sexp[n]/sqrt(m), eps') staged.
// Partials to dead buffers, NO atomics: ch0->KV, ch1/ch2->Qp, ch3->d_out.
// ---------------------------------------------------------------------------
__global__ __launch_bounds__(256) __attribute__((amdgpu_waves_per_eu(2, 8)))
void kv_kernel(
    const float* __restrict__ A, const float* __restrict__ V,
    const float* __restrict__ sexp,
    float* __restrict__ KV, float* __restrict__ P1,
    float* __restrict__ P2, float* __restrict__ P3,
    float* __restrict__ Ksum, float* __restrict__ KsumP)
{
    __shared__ __align__(16) float Kps[32][128];  // [n][m]
    __shared__ __align__(16) float Vs[32][128];   // [n][v]

    const int tid = threadIdx.x;
    const int tx = tid & 15, ty = tid >> 4;       // tx: v-cols, ty: m-rows ty*8..+7
    const int vt = blockIdx.x, mt = blockIdx.y;
    const int b  = blockIdx.z >> 2, ch = blockIdx.z & 3;
    const int m0 = mt * 128, v0 = vt * 128;
    const size_t n0 = (size_t)b * NPB + ch * 128;

    const int ln  = tid >> 5;     // 0..7  (n within chunk, +8j)
    const int lm4 = tid & 31;     // float4 column

    float acc[8][8] = {};
    float4 ks4 = {0.f, 0.f, 0.f, 0.f};

    for (int c = 0; c < 4; ++c) {
        __syncthreads();
        #pragma unroll
        for (int j = 0; j < 4; ++j) {
            const size_t n = n0 + c * 32 + ln + 8 * j;
            float4 a  = *(const float4*)&A[n * MF + m0 + lm4 * 4];
            float4 vv = *(const float4*)&V[n * DVV + v0 + lm4 * 4];
            const float s2 = sexp[n] * INV_SQRT_M;
            float4 e;
            e.x = fmaf(a.x, s2, EPS_ISM);
            e.y = fmaf(a.y, s2, EPS_ISM);
            e.z = fmaf(a.z, s2, EPS_ISM);
            e.w = fmaf(a.w, s2, EPS_ISM);
            ks4.x += e.x; ks4.y += e.y; ks4.z += e.z; ks4.w += e.w;
            *(float4*)&Kps[ln + 8 * j][lm4 * 4] = e;
            *(float4*)&Vs [ln + 8 * j][lm4 * 4] = vv;
        }
        __syncthreads();
        #pragma unroll 4
        for (int kk = 0; kk < 32; ++kk) {
            float4 a0 = *(const float4*)&Kps[kk][ty * 8];
            float4 a1 = *(const float4*)&Kps[kk][ty * 8 + 4];
            float4 b0 = *(const float4*)&Vs[kk][tx * 4];
            float4 b1 = *(const float4*)&Vs[kk][64 + tx * 4];
            float av[8] = {a0.x, a0.y, a0.z, a0.w, a1.x, a1.y, a1.z, a1.w};
            float bv[8] = {b0.x, b0.y, b0.z, b0.w, b1.x, b1.y, b1.z, b1.w};
            #pragma unroll
            for (int i = 0; i < 8; ++i)
                #pragma unroll
                for (int j = 0; j < 8; ++j)
                    acc[i][j] = fmaf(av[i], bv[j], acc[i][j]);
        }
    }

    float* __restrict__ dKV = (ch == 0) ? KV : (ch == 1) ? P1 : (ch == 2) ? P2 : P3;
    #pragma unroll
    for (int i = 0; i < 8; ++i) {
        const size_t base = ((size_t)b * MF + m0 + ty * 8 + i) * DVV + v0;
        float4 o0 = {acc[i][0], acc[i][1], acc[i][2], acc[i][3]};
        float4 o1 = {acc[i][4], acc[i][5], acc[i][6], acc[i][7]};
        *(float4*)&dKV[base + tx * 4]      = o0;
        *(float4*)&dKV[base + 64 + tx * 4] = o1;
    }

    if (vt == 0) {
        __syncthreads();                       // compute reads of Kps done
        *(float4*)&Kps[ln][lm4 * 4] = ks4;     // scratch [8][128]
        __syncthreads();
        if (tid < 128) {
            float s = 0.f;
            #pragma unroll
            for (int g = 0; g < 8; ++g) s += Kps[g][tid];
            float* dst = (ch == 0) ? (Ksum + b * MF)
                                   : (KsumP + ((ch - 1) * NB + b) * MF);
            dst[m0 + tid] = s;
        }
    }
}

// ---------------------------------------------------------------------------
// Kernel 3b: fold the three partial buffers into KV / Ksum.
// ---------------------------------------------------------------------------
__global__ __launch_bounds__(256) void kvreduce_kernel(
    float* __restrict__ KV, const float* __restrict__ P1,
    const float* __restrict__ P2, const float* __restrict__ P3,
    float* __restrict__ Ksum, const float* __restrict__ KsumP)
{
    const int idx = blockIdx.x * 256 + threadIdx.x;
    const int stride = gridDim.x * 256;
    const int TOT4 = NB * MF * DVV / 4;
    for (int i = idx; i < TOT4; i += stride) {
        float4 a  = ((const float4*)KV)[i];
        float4 p1 = ((const float4*)P1)[i];
        float4 p2 = ((const float4*)P2)[i];
        float4 p3 = ((const float4*)P3)[i];
        a.x += p1.x + p2.x + p3.x;
        a.y += p1.y + p2.y + p3.y;
        a.z += p1.z + p2.z + p3.z;
        a.w += p1.w + p2.w + p3.w;
        ((float4*)KV)[i] = a;
    }
    const int KS4 = NB * MF / 4;
    for (int i = idx; i < KS4; i += stride) {
        float4 a  = ((const float4*)Ksum)[i];
        float4 p1 = ((const float4*)KsumP)[i];
        float4 p2 = ((const float4*)KsumP)[i + KS4];
        float4 p3 = ((const float4*)KsumP)[i + 2 * KS4];
        a.x += p1.x + p2.x + p3.x;
        a.y += p1.y + p2.y + p3.y;
        a.z += p1.z + p2.z + p3.z;
        a.w += p1.w + p2.w + p3.w;
        ((float4*)Ksum)[i] = a;
    }
}

// ---------------------------------------------------------------------------
// Kernel 4: out = (Qp @ KV[b]) / (norm + eps). 128 rows x 128 v per block.
// Qp chunk staged TRANSPOSED (QsT[k][row]) -> A-frag = 8 contiguous floats
// = 2x b128 (was 8 scalar broadcasts). No prefetch regs: live ~88, no spill.
// B-frag cols split (tx*4, 64+tx*4), conflict-free.
// ---------------------------------------------------------------------------
__global__ __launch_bounds__(256) __attribute__((amdgpu_waves_per_eu(2, 8)))
void out_kernel(
    const float* __restrict__ Qp, const float* __restrict__ KVm,
    const float* __restrict__ normv, float* __restrict__ out)
{
    __shared__ __align__(16) float QsT[32][132];  // transposed: [k(m)][row]; 132 -> base 16B-aligned
    __shared__ __align__(16) float KVs[32][128];  // k-major
    __shared__ float nrmS[128];

    const int tid = threadIdx.x;
    const int tx = tid & 15, ty = tid >> 4;       // tx: v-cols, ty: rows ty*8..+7
    const int vt = blockIdx.x, rt = blockIdx.y, b = blockIdx.z;
    const int v0 = vt * 128;
    const int r0 = b * NPB + rt * 128;

    if (tid < 128) nrmS[tid] = normv[r0 + tid];

    const int qr  = tid >> 3;     // 0..31 (+32j): row being staged
    const int qm4 = tid & 7;      // k-float4 being staged
    const int km  = tid >> 5;     // 0..7  (+8j)
    const int kv4 = tid & 31;

    float acc[8][8] = {};

    for (int c = 0; c < 8; ++c) {
        __syncthreads();
        const int mc = c * 32;
        #pragma unroll
        for (int j = 0; j < 4; ++j) {
            float4 q = *(const float4*)&Qp[(size_t)(r0 + qr + 32 * j) * MF + mc + qm4 * 4];
            QsT[qm4 * 4 + 0][qr + 32 * j] = q.x;
            QsT[qm4 * 4 + 1][qr + 32 * j] = q.y;
            QsT[qm4 * 4 + 2][qr + 32 * j] = q.z;
            QsT[qm4 * 4 + 3][qr + 32 * j] = q.w;
            *(float4*)&KVs[km + 8 * j][kv4 * 4] =
                *(const float4*)&KVm[((size_t)b * MF + mc + km + 8 * j) * DVV + v0 + kv4 * 4];
        }
        __syncthreads();
        #pragma unroll 4
        for (int kk = 0; kk < 32; ++kk) {
            float4 a0 = *(const float4*)&QsT[kk][ty * 8];
            float4 a1 = *(const float4*)&QsT[kk][ty * 8 + 4];
            float4 b0 = *(const float4*)&KVs[kk][tx * 4];
            float4 b1 = *(const float4*)&KVs[kk][64 + tx * 4];
            float av[8] = {a0.x, a0.y, a0.z, a0.w, a1.x, a1.y, a1.z, a1.w};
            float bv[8] = {b0.x, b0.y, b0.z, b0.w, b1.x, b1.y, b1.z, b1.w};
            #pragma unroll
            for (int i = 0; i < 8; ++i)
                #pragma unroll
                for (int j = 0; j < 8; ++j)
                    acc[i][j] = fmaf(av[i], bv[j], acc[i][j]);
        }
    }

    #pragma unroll
    for (int i = 0; i < 8; ++i) {
        const int row = ty * 8 + i;
        const float inv = 1.0f / (nrmS[row] + EPS_NORM);
        float4 o0 = {acc[i][0] * inv, acc[i][1] * inv, acc[i][2] * inv, acc[i][3] * inv};
        float4 o1 = {acc[i][4] * inv, acc[i][5] * inv, acc[i][6] * inv, acc[i][7] * inv};
        const size_t base = (size_t)(r0 + row) * DVV + v0;
        *(float4*)&out[base + tx * 4]      = o0;
        *(float4*)&out[base + 64 + tx * 4] = o1;
    }
}

// ---------------------------------------------------------------------------
extern "C" void kernel_launch(void* const* d_in, const int* in_sizes, int n_in,
                              void* d_out, int out_size, void* d_ws, size_t ws_size,
                              hipStream_t stream)
{
    const float* Q     = (const float*)d_in[0];
    const float* K     = (const float*)d_in[1];
    const float* V     = (const float*)d_in[2];
    const float* omega = (const float*)d_in[3];
    float* out = (float*)d_out;

    float* ws    = (float*)d_ws;
    float* Qp    = ws;                              // N*M  (holds P1,P2 during kv)
    float* A     = Qp    + (size_t)NTOT * MF;       // N*M   A' = exp(U-h-rmax)
    float* KV    = A     + (size_t)NTOT * MF;       // B*M*DV
    float* Ksum  = KV    + (size_t)NB * MF * DVV;   // B*M
    float* KsumP = Ksum  + (size_t)NB * MF;         // 3 * B*M
    float* rmaxA = KsumP + (size_t)3 * NB * MF;     // N
    float* sexp  = rmaxA + NTOT;                    // N
    float* normv = sexp  + NTOT;                    // N

    float* P1 = Qp;                                 // dead until phi_Q
    float* P2 = Qp + (size_t)NB * MF * DVV;
    float* P3 = out;                                // dead until out_kernel

    phi_kernel<false><<<NTOT / 64, 256, 0, stream>>>(K, omega, (const float*)nullptr, A, rmaxA);
    segsexp_kernel<<<NB, 256, 0, stream>>>(rmaxA, sexp);
    kv_kernel<<<dim3(2, 2, NB * 4), 256, 0, stream>>>(A, V, sexp, KV, P1, P2, P3, Ksum, KsumP);
    kvreduce_kernel<<<2048, 256, 0, stream>>>(KV, P1, P2, P3, Ksum, KsumP);
    phi_kernel<true ><<<NTOT / 64, 256, 0, stream>>>(Q, omega, Ksum, Qp, normv);
    out_kernel<<<dim3(2, 4, NB), 256, 0, stream>>>(Qp, KV, normv, out);
}

// Round 9
// 276.841 us; speedup vs baseline: 1.3765x; 1.1351x over previous
//
#include <hip/hip_runtime.h>
#include <math.h>

// Problem constants (fixed by the reference setup)
#define NTOT 32768
#define NB   64
#define NPB  512      // rows per segment
#define DQK  128
#define MF   256      // feature count m
#define DVV  256      // value dim

#define QK_SCALE   0.29730177875068026f   // 128^-0.25
#define INV_SQRT_M 0.0625f                // 1/sqrt(256)
#define EPS_PHI    1e-4f
#define EPS_NORM   1e-8f
#define EPS_ISM    (EPS_PHI * INV_SQRT_M)

typedef float f32x4  __attribute__((ext_vector_type(4)));
typedef short bf16x8 __attribute__((ext_vector_type(8)));
typedef unsigned short us4 __attribute__((ext_vector_type(4)));
typedef unsigned short us8 __attribute__((ext_vector_type(8)));

static __device__ __forceinline__ float red_max32(float v) {
    v = fmaxf(v, __shfl_xor(v, 1, 64));
    v = fmaxf(v, __shfl_xor(v, 2, 64));
    v = fmaxf(v, __shfl_xor(v, 4, 64));
    v = fmaxf(v, __shfl_xor(v, 8, 64));
    v = fmaxf(v, __shfl_xor(v, 16, 64));
    return v;
}
static __device__ __forceinline__ float red_sum32(float v) {
    v += __shfl_xor(v, 1, 64);
    v += __shfl_xor(v, 2, 64);
    v += __shfl_xor(v, 4, 64);
    v += __shfl_xor(v, 8, 64);
    v += __shfl_xor(v, 16, 64);
    return v;
}

// split f32 into bf16 hi + bf16 lo (RNE both): hi+lo ~ x to ~2^-17 rel.
static __device__ __forceinline__ void bfsplit(float x, unsigned short& h, unsigned short& l) {
    unsigned u = __float_as_uint(x);
    unsigned r = (u + 0x7fffu + ((u >> 16) & 1u)) & 0xffff0000u;
    h = (unsigned short)(r >> 16);
    float lo = x - __uint_as_float(r);
    unsigned v = __float_as_uint(lo);
    l = (unsigned short)((v + 0x7fffu + ((v >> 16) & 1u)) >> 16);
}

// ---------------------------------------------------------------------------
// Kernel 1: U = (X * d^-1/4) @ omega  (unchanged from r8 — best measured)
// ---------------------------------------------------------------------------
template <bool IS_QUERY>
__global__ __launch_bounds__(256) __attribute__((amdgpu_waves_per_eu(2, 8)))
void phi_kernel(
    const float* __restrict__ X, const float* __restrict__ omega,
    const float* __restrict__ Ksum,
    float* __restrict__ out, float* __restrict__ aux)
{
    __shared__ __align__(16) float xsT[128][68];  // transposed: [k][row]
    __shared__ __align__(16) float oms[16][256];  // k-major omega chunk
    __shared__ float KsS[256];

    const int tid = threadIdx.x;
    const int tx  = tid & 31;
    const int ty  = tid >> 5;
    const int row0 = blockIdx.x * 64;

    if (IS_QUERY) KsS[tid] = Ksum[(row0 >> 9) * MF + tid];

    {
        const float4* Xv = (const float4*)(X + (size_t)row0 * DQK);
        #pragma unroll
        for (int j = 0; j < 8; ++j) {
            int idx = tid + 256 * j;
            int r = idx >> 5, c4 = idx & 31;
            float4 v = Xv[idx];
            xsT[c4 * 4 + 0][r] = v.x * QK_SCALE;
            xsT[c4 * 4 + 1][r] = v.y * QK_SCALE;
            xsT[c4 * 4 + 2][r] = v.z * QK_SCALE;
            xsT[c4 * 4 + 3][r] = v.w * QK_SCALE;
        }
    }

    float acc[8][8] = {};
    float h[8] = {};

    const float4* Ov = (const float4*)omega;

    for (int c = 0; c < 8; ++c) {
        __syncthreads();
        #pragma unroll
        for (int j = 0; j < 4; ++j) {
            int idx = tid + 256 * j;
            *(float4*)&oms[idx >> 6][(idx & 63) * 4] = Ov[c * 1024 + idx];
        }
        __syncthreads();
        const int kc = c * 16;
        #pragma unroll 2
        for (int kk = 0; kk < 16; ++kk) {
            float4 a0 = *(const float4*)&xsT[kc + kk][ty * 8];
            float4 a1 = *(const float4*)&xsT[kc + kk][ty * 8 + 4];
            float4 b0 = *(const float4*)&oms[kk][tx * 4];
            float4 b1 = *(const float4*)&oms[kk][128 + tx * 4];
            float av[8] = {a0.x, a0.y, a0.z, a0.w, a1.x, a1.y, a1.z, a1.w};
            float bv[8] = {b0.x, b0.y, b0.z, b0.w, b1.x, b1.y, b1.z, b1.w};
            #pragma unroll
            for (int i = 0; i < 8; ++i) {
                h[i] = fmaf(av[i], av[i], h[i]);
                #pragma unroll
                for (int j = 0; j < 8; ++j)
                    acc[i][j] = fmaf(av[i], bv[j], acc[i][j]);
            }
        }
    }

    #pragma unroll
    for (int i = 0; i < 8; ++i) {
        const int grow = row0 + ty * 8 + i;
        float mx = acc[i][0];
        #pragma unroll
        for (int j = 1; j < 8; ++j) mx = fmaxf(mx, acc[i][j]);
        mx = red_max32(mx);
        const float hm = 0.5f * h[i] + mx;

        if (IS_QUERY) {
            float q[8];
            #pragma unroll
            for (int j = 0; j < 8; ++j)
                q[j] = (__expf(acc[i][j] - hm) + EPS_PHI) * INV_SQRT_M;
            float4 o0 = {q[0], q[1], q[2], q[3]};
            float4 o1 = {q[4], q[5], q[6], q[7]};
            *(float4*)&out[(size_t)grow * MF + tx * 4]       = o0;
            *(float4*)&out[(size_t)grow * MF + 128 + tx * 4] = o1;
            float np = 0.f;
            #pragma unroll
            for (int j = 0; j < 4; ++j) np = fmaf(q[j], KsS[tx * 4 + j], np);
            #pragma unroll
            for (int j = 0; j < 4; ++j) np = fmaf(q[4 + j], KsS[128 + tx * 4 + j], np);
            np = red_sum32(np);
            if (tx == 0) aux[grow] = np;
        } else {
            float4 o0 = {__expf(acc[i][0] - hm), __expf(acc[i][1] - hm),
                         __expf(acc[i][2] - hm), __expf(acc[i][3] - hm)};
            float4 o1 = {__expf(acc[i][4] - hm), __expf(acc[i][5] - hm),
                         __expf(acc[i][6] - hm), __expf(acc[i][7] - hm)};
            *(float4*)&out[(size_t)grow * MF + tx * 4]       = o0;
            *(float4*)&out[(size_t)grow * MF + 128 + tx * 4] = o1;
            if (tx == 0) aux[grow] = mx;
        }
    }
}

// ---------------------------------------------------------------------------
// Kernel 2: sexp[n] = exp(rmax[n] - max_{segment} rmax)  (unchanged)
// ---------------------------------------------------------------------------
__global__ __launch_bounds__(256) void segsexp_kernel(
    const float* __restrict__ rmax, float* __restrict__ sexp)
{
    const int b = blockIdx.x, tid = threadIdx.x;
    const float r0 = rmax[b * NPB + tid];
    const float r1 = rmax[b * NPB + 256 + tid];
    float v = fmaxf(r0, r1);
    v = red_max32(v);
    v = fmaxf(v, __shfl_xor(v, 32, 64));
    __shared__ float red[4];
    if ((tid & 63) == 0) red[tid >> 6] = v;
    __syncthreads();
    const float smax = fmaxf(fmaxf(red[0], red[1]), fmaxf(red[2], red[3]));
    sexp[b * NPB + tid]       = __expf(r0 - smax);
    sexp[b * NPB + 256 + tid] = __expf(r1 - smax);
}

// ---------------------------------------------------------------------------
// Kernel 3: KV partials (unchanged from r8)
// ---------------------------------------------------------------------------
__global__ __launch_bounds__(256) __attribute__((amdgpu_waves_per_eu(2, 8)))
void kv_kernel(
    const float* __restrict__ A, const float* __restrict__ V,
    const float* __restrict__ sexp,
    float* __restrict__ KV, float* __restrict__ P1,
    float* __restrict__ P2, float* __restrict__ P3,
    float* __restrict__ Ksum, float* __restrict__ KsumP)
{
    __shared__ __align__(16) float Kps[32][128];  // [n][m]
    __shared__ __align__(16) float Vs[32][128];   // [n][v]

    const int tid = threadIdx.x;
    const int tx = tid & 15, ty = tid >> 4;
    const int vt = blockIdx.x, mt = blockIdx.y;
    const int b  = blockIdx.z >> 2, ch = blockIdx.z & 3;
    const int m0 = mt * 128, v0 = vt * 128;
    const size_t n0 = (size_t)b * NPB + ch * 128;

    const int ln  = tid >> 5;
    const int lm4 = tid & 31;

    float acc[8][8] = {};
    float4 ks4 = {0.f, 0.f, 0.f, 0.f};

    for (int c = 0; c < 4; ++c) {
        __syncthreads();
        #pragma unroll
        for (int j = 0; j < 4; ++j) {
            const size_t n = n0 + c * 32 + ln + 8 * j;
            float4 a  = *(const float4*)&A[n * MF + m0 + lm4 * 4];
            float4 vv = *(const float4*)&V[n * DVV + v0 + lm4 * 4];
            const float s2 = sexp[n] * INV_SQRT_M;
            float4 e;
            e.x = fmaf(a.x, s2, EPS_ISM);
            e.y = fmaf(a.y, s2, EPS_ISM);
            e.z = fmaf(a.z, s2, EPS_ISM);
            e.w = fmaf(a.w, s2, EPS_ISM);
            ks4.x += e.x; ks4.y += e.y; ks4.z += e.z; ks4.w += e.w;
            *(float4*)&Kps[ln + 8 * j][lm4 * 4] = e;
            *(float4*)&Vs [ln + 8 * j][lm4 * 4] = vv;
        }
        __syncthreads();
        #pragma unroll 4
        for (int kk = 0; kk < 32; ++kk) {
            float4 a0 = *(const float4*)&Kps[kk][ty * 8];
            float4 a1 = *(const float4*)&Kps[kk][ty * 8 + 4];
            float4 b0 = *(const float4*)&Vs[kk][tx * 4];
            float4 b1 = *(const float4*)&Vs[kk][64 + tx * 4];
            float av[8] = {a0.x, a0.y, a0.z, a0.w, a1.x, a1.y, a1.z, a1.w};
            float bv[8] = {b0.x, b0.y, b0.z, b0.w, b1.x, b1.y, b1.z, b1.w};
            #pragma unroll
            for (int i = 0; i < 8; ++i)
                #pragma unroll
                for (int j = 0; j < 8; ++j)
                    acc[i][j] = fmaf(av[i], bv[j], acc[i][j]);
        }
    }

    float* __restrict__ dKV = (ch == 0) ? KV : (ch == 1) ? P1 : (ch == 2) ? P2 : P3;
    #pragma unroll
    for (int i = 0; i < 8; ++i) {
        const size_t base = ((size_t)b * MF + m0 + ty * 8 + i) * DVV + v0;
        float4 o0 = {acc[i][0], acc[i][1], acc[i][2], acc[i][3]};
        float4 o1 = {acc[i][4], acc[i][5], acc[i][6], acc[i][7]};
        *(float4*)&dKV[base + tx * 4]      = o0;
        *(float4*)&dKV[base + 64 + tx * 4] = o1;
    }

    if (vt == 0) {
        __syncthreads();
        *(float4*)&Kps[ln][lm4 * 4] = ks4;
        __syncthreads();
        if (tid < 128) {
            float s = 0.f;
            #pragma unroll
            for (int g = 0; g < 8; ++g) s += Kps[g][tid];
            float* dst = (ch == 0) ? (Ksum + b * MF)
                                   : (KsumP + ((ch - 1) * NB + b) * MF);
            dst[m0 + tid] = s;
        }
    }
}

// ---------------------------------------------------------------------------
// Kernel 3b: fold partials (unchanged)
// ---------------------------------------------------------------------------
__global__ __launch_bounds__(256) void kvreduce_kernel(
    float* __restrict__ KV, const float* __restrict__ P1,
    const float* __restrict__ P2, const float* __restrict__ P3,
    float* __restrict__ Ksum, const float* __restrict__ KsumP)
{
    const int idx = blockIdx.x * 256 + threadIdx.x;
    const int stride = gridDim.x * 256;
    const int TOT4 = NB * MF * DVV / 4;
    for (int i = idx; i < TOT4; i += stride) {
        float4 a  = ((const float4*)KV)[i];
        float4 p1 = ((const float4*)P1)[i];
        float4 p2 = ((const float4*)P2)[i];
        float4 p3 = ((const float4*)P3)[i];
        a.x += p1.x + p2.x + p3.x;
        a.y += p1.y + p2.y + p3.y;
        a.z += p1.z + p2.z + p3.z;
        a.w += p1.w + p2.w + p3.w;
        ((float4*)KV)[i] = a;
    }
    const int KS4 = NB * MF / 4;
    for (int i = idx; i < KS4; i += stride) {
        float4 a  = ((const float4*)Ksum)[i];
        float4 p1 = ((const float4*)KsumP)[i];
        float4 p2 = ((const float4*)KsumP)[i + KS4];
        float4 p3 = ((const float4*)KsumP)[i + 2 * KS4];
        a.x += p1.x + p2.x + p3.x;
        a.y += p1.y + p2.y + p3.y;
        a.z += p1.z + p2.z + p3.z;
        a.w += p1.w + p2.w + p3.w;
        ((float4*)Ksum)[i] = a;
    }
}

// ---------------------------------------------------------------------------
// Kernel 4 (REWRITTEN, r9): out = (Qp @ KV[b]) / (norm + eps) via bf16-split
// MFMA (3 terms: AhBh + AhBl + AlBh; fp32 accumulate; rel err ~2^-16).
// 128 rows x 128 v per block, 4 waves -> one 64x64 quadrant each (16 tiles
// of mfma_f32_16x16x32_bf16, acc 64 f32/lane in the unified VGPR/AGPR file).
// K = m, 8 chunks of 32. Staging per chunk:
//   phase A: Qp tile -> bf16 hi/lo (natural row-major, b64 writes) and
//            KV tile -> f32 LDS bounce Kf[32 m][132] (coalesced, padded);
//   phase B: transpose-read Kf columns (conflict-free: 32 distinct v-banks,
//            lane pairs broadcast) -> convert -> Kh/Kl[v][m] rows (b128).
// Fragment layouts: A row = lane&15, B col = lane&15, k-slice = (lane>>4)*8
// (any common k-permutation is correct by dot-product invariance); C/D:
// col = lane&15, row = (lane>>4)*4 + reg [HW-verified mapping].
// ---------------------------------------------------------------------------
__global__ __launch_bounds__(256) void out_kernel(
    const float* __restrict__ Qp, const float* __restrict__ KVm,
    const float* __restrict__ normv, float* __restrict__ out)
{
    __shared__ __align__(16) unsigned short Qh[128][40];  // bf16 hi of Qp tile
    __shared__ __align__(16) unsigned short Ql[128][40];  // bf16 lo
    __shared__ __align__(16) unsigned short Kh[128][40];  // bf16 hi of KV^T tile [v][m]
    __shared__ __align__(16) unsigned short Kl[128][40];  // bf16 lo
    __shared__ __align__(16) float Kf[32][132];           // f32 bounce [m][v]
    __shared__ float nrmS[128];

    const int tid  = threadIdx.x;
    const int lane = tid & 63;
    const int w    = tid >> 6;        // wave 0..3
    const int wr   = w >> 1;          // row-quadrant 0..1
    const int wc   = w & 1;           // col-quadrant 0..1
    const int fr   = lane & 15;       // row/col within 16x16 tile
    const int k8   = (lane >> 4) * 8; // k-slice start within 32-chunk

    const int vt = blockIdx.x, rt = blockIdx.y, b = blockIdx.z;
    const int v0 = vt * 128;
    const int r0 = b * NPB + rt * 128;

    if (tid < 128) nrmS[tid] = normv[r0 + tid];

    const int qr  = tid >> 3;   // 0..31 (+32j): Q staging row
    const int qm4 = tid & 7;    // Q staging k-float4
    const int km  = tid >> 5;   // 0..7 (+8j):  KV staging m-row
    const int kv4 = tid & 31;   // KV staging v-float4
    const int tv  = tid >> 1;   // 0..127: transpose-pass v
    const int th  = tid & 1;    // transpose-pass m-half

    f32x4 acc[4][4] = {};       // [row-tile][col-tile]

    for (int c = 0; c < 8; ++c) {
        const int mc = c * 32;
        __syncthreads();
        // ---- phase A: Q -> bf16 hi/lo (natural layout); KV -> f32 bounce ----
        #pragma unroll
        for (int j = 0; j < 4; ++j) {
            float4 q = *(const float4*)&Qp[(size_t)(r0 + qr + 32 * j) * MF + mc + qm4 * 4];
            unsigned short h0, l0, h1, l1, h2, l2, h3, l3;
            bfsplit(q.x, h0, l0); bfsplit(q.y, h1, l1);
            bfsplit(q.z, h2, l2); bfsplit(q.w, h3, l3);
            us4 hv = {h0, h1, h2, h3};
            us4 lv = {l0, l1, l2, l3};
            *(us4*)&Qh[qr + 32 * j][qm4 * 4] = hv;
            *(us4*)&Ql[qr + 32 * j][qm4 * 4] = lv;

            *(float4*)&Kf[km + 8 * j][kv4 * 4] =
                *(const float4*)&KVm[((size_t)b * MF + mc + km + 8 * j) * DVV + v0 + kv4 * 4];
        }
        __syncthreads();
        // ---- phase B: transpose-read Kf columns -> Kh/Kl[v][m] ----
        {
            unsigned short hh[16], ll[16];
            #pragma unroll
            for (int s = 0; s < 16; ++s)
                bfsplit(Kf[th * 16 + s][tv], hh[s], ll[s]);
            *(us8*)&Kh[tv][th * 16]     = *(us8*)&hh[0];
            *(us8*)&Kh[tv][th * 16 + 8] = *(us8*)&hh[8];
            *(us8*)&Kl[tv][th * 16]     = *(us8*)&ll[0];
            *(us8*)&Kl[tv][th * 16 + 8] = *(us8*)&ll[8];
        }
        __syncthreads();
        // ---- MFMA: 16 tiles x 3 split-terms ----
        bf16x8 ah[4], al[4];
        #pragma unroll
        for (int t = 0; t < 4; ++t) {
            ah[t] = *(const bf16x8*)&Qh[wr * 64 + t * 16 + fr][k8];
            al[t] = *(const bf16x8*)&Ql[wr * 64 + t * 16 + fr][k8];
        }
        #pragma unroll
        for (int u = 0; u < 4; ++u) {
            bf16x8 bh = *(const bf16x8*)&Kh[wc * 64 + u * 16 + fr][k8];
            bf16x8 bl = *(const bf16x8*)&Kl[wc * 64 + u * 16 + fr][k8];
            #pragma unroll
            for (int t = 0; t < 4; ++t) {
                acc[t][u] = __builtin_amdgcn_mfma_f32_16x16x32_bf16(ah[t], bh, acc[t][u], 0, 0, 0);
                acc[t][u] = __builtin_amdgcn_mfma_f32_16x16x32_bf16(ah[t], bl, acc[t][u], 0, 0, 0);
                acc[t][u] = __builtin_amdgcn_mfma_f32_16x16x32_bf16(al[t], bh, acc[t][u], 0, 0, 0);
            }
        }
    }

    // ---- epilogue: C/D layout col=lane&15, row=(lane>>4)*4+g ----
    const int rg = (lane >> 4) * 4;
    #pragma unroll
    for (int t = 0; t < 4; ++t) {
        #pragma unroll
        for (int g = 0; g < 4; ++g) {
            const int row = wr * 64 + t * 16 + rg + g;
            const float inv = 1.0f / (nrmS[row] + EPS_NORM);
            const size_t base = (size_t)(r0 + row) * DVV + v0 + wc * 64;
            #pragma unroll
            for (int u = 0; u < 4; ++u)
                out[base + u * 16 + fr] = acc[t][u][g] * inv;
        }
    }
}

// ---------------------------------------------------------------------------
extern "C" void kernel_launch(void* const* d_in, const int* in_sizes, int n_in,
                              void* d_out, int out_size, void* d_ws, size_t ws_size,
                              hipStream_t stream)
{
    const float* Q     = (const float*)d_in[0];
    const float* K     = (const float*)d_in[1];
    const float* V     = (const float*)d_in[2];
    const float* omega = (const float*)d_in[3];
    float* out = (float*)d_out;

    float* ws    = (float*)d_ws;
    float* Qp    = ws;                              // N*M  (holds P1,P2 during kv)
    float* A     = Qp    + (size_t)NTOT * MF;       // N*M   A' = exp(U-h-rmax)
    float* KV    = A     + (size_t)NTOT * MF;       // B*M*DV
    float* Ksum  = KV    + (size_t)NB * MF * DVV;   // B*M
    float* KsumP = Ksum  + (size_t)NB * MF;         // 3 * B*M
    float* rmaxA = KsumP + (size_t)3 * NB * MF;     // N
    float* sexp  = rmaxA + NTOT;                    // N
    float* normv = sexp  + NTOT;                    // N

    float* P1 = Qp;                                 // dead until phi_Q
    float* P2 = Qp + (size_t)NB * MF * DVV;
    float* P3 = out;                                // dead until out_kernel

    phi_kernel<false><<<NTOT / 64, 256, 0, stream>>>(K, omega, (const float*)nullptr, A, rmaxA);
    segsexp_kernel<<<NB, 256, 0, stream>>>(rmaxA, sexp);
    kv_kernel<<<dim3(2, 2, NB * 4), 256, 0, stream>>>(A, V, sexp, KV, P1, P2, P3, Ksum, KsumP);
    kvreduce_kernel<<<2048, 256, 0, stream>>>(KV, P1, P2, P3, Ksum, KsumP);
    phi_kernel<true ><<<NTOT / 64, 256, 0, stream>>>(Q, omega, Ksum, Qp, normv);
    out_kernel<<<dim3(2, 4, NB), 256, 0, stream>>>(Qp, KV, normv, out);
}

// Round 10
// 222.635 us; speedup vs baseline: 1.7116x; 1.2435x over previous
//
#include <hip/hip_runtime.h>
#include <math.h>

// Problem constants (fixed by the reference setup)
#define NTOT 32768
#define NB   64
#define NPB  512      // rows per segment
#define DQK  128
#define MF   256      // feature count m
#define DVV  256      // value dim

#define QK_SCALE   0.29730177875068026f   // 128^-0.25
#define INV_SQRT_M 0.0625f                // 1/sqrt(256)
#define EPS_PHI    1e-4f
#define EPS_NORM   1e-8f
#define EPS_ISM    (EPS_PHI * INV_SQRT_M)

typedef float f32x4  __attribute__((ext_vector_type(4)));
typedef short bf16x8 __attribute__((ext_vector_type(8)));
typedef unsigned short us4 __attribute__((ext_vector_type(4)));
typedef unsigned short us8 __attribute__((ext_vector_type(8)));

static __device__ __forceinline__ float red_max32(float v) {
    v = fmaxf(v, __shfl_xor(v, 1, 64));
    v = fmaxf(v, __shfl_xor(v, 2, 64));
    v = fmaxf(v, __shfl_xor(v, 4, 64));
    v = fmaxf(v, __shfl_xor(v, 8, 64));
    v = fmaxf(v, __shfl_xor(v, 16, 64));
    return v;
}
static __device__ __forceinline__ float red_sum32(float v) {
    v += __shfl_xor(v, 1, 64);
    v += __shfl_xor(v, 2, 64);
    v += __shfl_xor(v, 4, 64);
    v += __shfl_xor(v, 8, 64);
    v += __shfl_xor(v, 16, 64);
    return v;
}
static __device__ __forceinline__ float red_sum16(float v) {
    v += __shfl_xor(v, 1, 64);
    v += __shfl_xor(v, 2, 64);
    v += __shfl_xor(v, 4, 64);
    v += __shfl_xor(v, 8, 64);
    return v;
}
static __device__ __forceinline__ float red_max16(float v) {
    v = fmaxf(v, __shfl_xor(v, 1, 64));
    v = fmaxf(v, __shfl_xor(v, 2, 64));
    v = fmaxf(v, __shfl_xor(v, 4, 64));
    v = fmaxf(v, __shfl_xor(v, 8, 64));
    return v;
}

// split f32 into bf16 hi + bf16 lo (RNE both): hi+lo ~ x to ~2^-17 rel.
static __device__ __forceinline__ void bfsplit(float x, unsigned short& h, unsigned short& l) {
    unsigned u = __float_as_uint(x);
    unsigned r = (u + 0x7fffu + ((u >> 16) & 1u)) & 0xffff0000u;
    h = (unsigned short)(r >> 16);
    float lo = x - __uint_as_float(r);
    unsigned v = __float_as_uint(lo);
    l = (unsigned short)((v + 0x7fffu + ((v >> 16) & 1u)) >> 16);
}

// ---------------------------------------------------------------------------
// Kernel 0: one-time omega^T bf16 hi/lo split: OmT[m][k] from omega[k][m].
// 32K elements, runs once (~2 us) — makes phi's B-operand a plain global
// read (131 KB, L2-resident, shared by all phi blocks; no LDS transpose).
// ---------------------------------------------------------------------------
__global__ __launch_bounds__(256) void omsplit_kernel(
    const float* __restrict__ omega,
    unsigned short* __restrict__ OmTh, unsigned short* __restrict__ OmTl)
{
    const int k = blockIdx.x;      // 0..127
    const int m = threadIdx.x;     // 0..255
    unsigned short h, l;
    bfsplit(omega[k * MF + m], h, l);
    OmTh[(size_t)m * DQK + k] = h;
    OmTl[(size_t)m * DQK + k] = l;
}

// ---------------------------------------------------------------------------
// Kernel 1 (MFMA, r10): U = (X * d^-1/4) @ omega, 64 rows x 256 m per block.
// A = X staged f32 once (Xf[64][132], 33.8 KB), fragments bfsplit in regs.
// B = OmTh/OmTl read DIRECT from global (L2-resident) — no barriers in the
// K-loop. 4 waves = 4 m-quadrants; 4 k-chunks x 16 tiles x 3 split terms.
// h computed exactly in f32 during staging (row = tid>>5 + 8j, 32-lane
// shuffle reduce). rowmax / norm: per-wave frag reduce + cross-wave LDS.
//   IS_QUERY: out = Qp; aux = norm.   else: out = exp(U-h-rowmax); aux = rowmax
// ---------------------------------------------------------------------------
template <bool IS_QUERY>
__global__ __launch_bounds__(256) void phi_kernel(
    const float* __restrict__ X,
    const unsigned short* __restrict__ OmTh, const unsigned short* __restrict__ OmTl,
    const float* __restrict__ Ksum,
    float* __restrict__ out, float* __restrict__ aux)
{
    __shared__ __align__(16) float Xf[64][132];
    __shared__ float hS[64];
    __shared__ float mxW[4][64];
    __shared__ float npW[4][64];
    __shared__ float KsS[256];

    const int tid  = threadIdx.x;
    const int lane = tid & 63;
    const int w    = tid >> 6;        // wave = m-quadrant 0..3
    const int fr   = lane & 15;
    const int k8   = (lane >> 4) * 8;
    const int rg   = (lane >> 4) * 4;
    const int row0 = blockIdx.x * 64;

    if (IS_QUERY) KsS[tid] = Ksum[(row0 >> 9) * MF + tid];

    // ---- stage X (scaled, natural [row][k]) + exact f32 h partials ----
    float hp[8];
    {
        const float4* Xv = (const float4*)(X + (size_t)row0 * DQK);
        #pragma unroll
        for (int j = 0; j < 8; ++j) {
            int idx = tid + 256 * j;
            int r = idx >> 5, c4 = idx & 31;
            float4 v = Xv[idx];
            v.x *= QK_SCALE; v.y *= QK_SCALE; v.z *= QK_SCALE; v.w *= QK_SCALE;
            *(float4*)&Xf[r][c4 * 4] = v;
            hp[j] = v.x * v.x + v.y * v.y + v.z * v.z + v.w * v.w;
        }
    }
    __syncthreads();
    #pragma unroll
    for (int j = 0; j < 8; ++j) hp[j] = red_sum32(hp[j]);
    if ((tid & 31) == 0) {
        #pragma unroll
        for (int j = 0; j < 8; ++j) hS[(tid >> 5) + 8 * j] = hp[j];
    }

    // ---- MFMA main loop (no barriers: Xf read-only, B from global) ----
    f32x4 acc[4][4] = {};    // [row-tile t][col-tile u]
    #pragma unroll
    for (int c = 0; c < 4; ++c) {
        bf16x8 ah[4], al[4];
        #pragma unroll
        for (int t = 0; t < 4; ++t) {
            float a[8];
            *(float4*)&a[0] = *(const float4*)&Xf[t * 16 + fr][c * 32 + k8];
            *(float4*)&a[4] = *(const float4*)&Xf[t * 16 + fr][c * 32 + k8 + 4];
            unsigned short hh[8], ll[8];
            #pragma unroll
            for (int s = 0; s < 8; ++s) bfsplit(a[s], hh[s], ll[s]);
            ah[t] = *(bf16x8*)&hh[0];
            al[t] = *(bf16x8*)&ll[0];
        }
        #pragma unroll
        for (int u = 0; u < 4; ++u) {
            const size_t ob = (size_t)(w * 64 + u * 16 + fr) * DQK + c * 32 + k8;
            bf16x8 bh = *(const bf16x8*)&OmTh[ob];
            bf16x8 bl = *(const bf16x8*)&OmTl[ob];
            #pragma unroll
            for (int t = 0; t < 4; ++t) {
                acc[t][u] = __builtin_amdgcn_mfma_f32_16x16x32_bf16(ah[t], bh, acc[t][u], 0, 0, 0);
                acc[t][u] = __builtin_amdgcn_mfma_f32_16x16x32_bf16(ah[t], bl, acc[t][u], 0, 0, 0);
                acc[t][u] = __builtin_amdgcn_mfma_f32_16x16x32_bf16(al[t], bh, acc[t][u], 0, 0, 0);
            }
        }
    }

    // ---- rowmax: per-lane over u, reduce over fr lanes, cross-wave LDS ----
    #pragma unroll
    for (int t = 0; t < 4; ++t) {
        #pragma unroll
        for (int g = 0; g < 4; ++g) {
            float m0 = fmaxf(fmaxf(acc[t][0][g], acc[t][1][g]),
                             fmaxf(acc[t][2][g], acc[t][3][g]));
            m0 = red_max16(m0);
            if (fr == 0) mxW[w][t * 16 + rg + g] = m0;
        }
    }
    __syncthreads();

    // ---- epilogue ----
    #pragma unroll
    for (int t = 0; t < 4; ++t) {
        #pragma unroll
        for (int g = 0; g < 4; ++g) {
            const int row  = t * 16 + rg + g;
            const int grow = row0 + row;
            const float mxa = fmaxf(fmaxf(mxW[0][row], mxW[1][row]),
                                    fmaxf(mxW[2][row], mxW[3][row]));
            const float hm = 0.5f * hS[row] + mxa;
            if (IS_QUERY) {
                float np = 0.f;
                #pragma unroll
                for (int u = 0; u < 4; ++u) {
                    const int col = w * 64 + u * 16 + fr;
                    const float q = (__expf(acc[t][u][g] - hm) + EPS_PHI) * INV_SQRT_M;
                    out[(size_t)grow * MF + col] = q;
                    np = fmaf(q, KsS[col], np);
                }
                np = red_sum16(np);
                if (fr == 0) npW[w][row] = np;
            } else {
                #pragma unroll
                for (int u = 0; u < 4; ++u)
                    out[(size_t)grow * MF + w * 64 + u * 16 + fr] = __expf(acc[t][u][g] - hm);
                if (w == 0 && fr == 0) aux[grow] = mxa;
            }
        }
    }
    if (IS_QUERY) {
        __syncthreads();
        if (w == 0 && fr == 0) {
            #pragma unroll
            for (int t = 0; t < 4; ++t)
                #pragma unroll
                for (int g = 0; g < 4; ++g) {
                    const int row = t * 16 + rg + g;
                    aux[row0 + row] = npW[0][row] + npW[1][row] + npW[2][row] + npW[3][row];
                }
        }
    }
}

// ---------------------------------------------------------------------------
// Kernel 2: sexp[n] = exp(rmax[n] - max_{segment} rmax)  (unchanged)
// ---------------------------------------------------------------------------
__global__ __launch_bounds__(256) void segsexp_kernel(
    const float* __restrict__ rmax, float* __restrict__ sexp)
{
    const int b = blockIdx.x, tid = threadIdx.x;
    const float r0 = rmax[b * NPB + tid];
    const float r1 = rmax[b * NPB + 256 + tid];
    float v = fmaxf(r0, r1);
    v = red_max32(v);
    v = fmaxf(v, __shfl_xor(v, 32, 64));
    __shared__ float red[4];
    if ((tid & 63) == 0) red[tid >> 6] = v;
    __syncthreads();
    const float smax = fmaxf(fmaxf(red[0], red[1]), fmaxf(red[2], red[3]));
    sexp[b * NPB + tid]       = __expf(r0 - smax);
    sexp[b * NPB + 256 + tid] = __expf(r1 - smax);
}

// ---------------------------------------------------------------------------
// Kernel 3 (MFMA, r10): KV partial = Kp_chunk^T @ V_chunk over 128 n.
// k = n (4 chunks of 32). Staging: phase A computes Kp = fmaf(A',sexp,eps)
// into f32 bounce Af[32][132] (+ exact-f32 ks4 for Ksum) and V into Vf;
// phase B transpose-reads columns (2-way, free) -> bfsplit -> KpH/KpL[m][n],
// VH/VL[v][n]. MFMA: 4 waves x 16 tiles x 3 terms x 4 chunks. Partials to
// dead buffers (no atomics) as before; kvreduce folds. LDS 73 KB -> 2/CU.
// ---------------------------------------------------------------------------
__global__ __launch_bounds__(256) void kv_kernel(
    const float* __restrict__ A, const float* __restrict__ V,
    const float* __restrict__ sexp,
    float* __restrict__ KV, float* __restrict__ P1,
    float* __restrict__ P2, float* __restrict__ P3,
    float* __restrict__ Ksum, float* __restrict__ KsumP)
{
    __shared__ __align__(16) float Af[32][132];
    __shared__ __align__(16) float Vf[32][132];
    __shared__ __align__(16) unsigned short KpH[128][40];
    __shared__ __align__(16) unsigned short KpL[128][40];
    __shared__ __align__(16) unsigned short VH[128][40];
    __shared__ __align__(16) unsigned short VL[128][40];

    const int tid  = threadIdx.x;
    const int lane = tid & 63;
    const int w    = tid >> 6;
    const int wr   = w >> 1;          // m-quadrant
    const int wc   = w & 1;           // v-quadrant
    const int fr   = lane & 15;
    const int k8   = (lane >> 4) * 8;
    const int rg   = (lane >> 4) * 4;

    const int vt = blockIdx.x, mt = blockIdx.y;
    const int b  = blockIdx.z >> 2, ch = blockIdx.z & 3;
    const int m0 = mt * 128, v0 = vt * 128;
    const size_t n0 = (size_t)b * NPB + ch * 128;

    const int ln  = tid >> 5;     // staging n row (+8j)
    const int lm4 = tid & 31;     // staging float4 col
    const int tv  = tid >> 1;     // transpose-pass output row (m or v)
    const int th  = tid & 1;      // transpose-pass n-half

    f32x4 acc[4][4] = {};
    float4 ks4 = {0.f, 0.f, 0.f, 0.f};

    for (int c = 0; c < 4; ++c) {
        __syncthreads();
        // ---- phase A: global -> f32 bounces (+ exact Ksum partials) ----
        #pragma unroll
        for (int j = 0; j < 4; ++j) {
            const size_t n = n0 + c * 32 + ln + 8 * j;
            float4 a  = *(const float4*)&A[n * MF + m0 + lm4 * 4];
            float4 vv = *(const float4*)&V[n * DVV + v0 + lm4 * 4];
            const float s2 = sexp[n] * INV_SQRT_M;
            float4 e;
            e.x = fmaf(a.x, s2, EPS_ISM);
            e.y = fmaf(a.y, s2, EPS_ISM);
            e.z = fmaf(a.z, s2, EPS_ISM);
            e.w = fmaf(a.w, s2, EPS_ISM);
            ks4.x += e.x; ks4.y += e.y; ks4.z += e.z; ks4.w += e.w;
            *(float4*)&Af[ln + 8 * j][lm4 * 4] = e;
            *(float4*)&Vf[ln + 8 * j][lm4 * 4] = vv;
        }
        __syncthreads();
        // ---- phase B: transpose-read + bfsplit -> bf16 [idx][n] tiles ----
        {
            unsigned short hh[16], ll[16];
            #pragma unroll
            for (int s = 0; s < 16; ++s)
                bfsplit(Af[th * 16 + s][tv], hh[s], ll[s]);
            *(us8*)&KpH[tv][th * 16]     = *(us8*)&hh[0];
            *(us8*)&KpH[tv][th * 16 + 8] = *(us8*)&hh[8];
            *(us8*)&KpL[tv][th * 16]     = *(us8*)&ll[0];
            *(us8*)&KpL[tv][th * 16 + 8] = *(us8*)&ll[8];
            #pragma unroll
            for (int s = 0; s < 16; ++s)
                bfsplit(Vf[th * 16 + s][tv], hh[s], ll[s]);
            *(us8*)&VH[tv][th * 16]     = *(us8*)&hh[0];
            *(us8*)&VH[tv][th * 16 + 8] = *(us8*)&hh[8];
            *(us8*)&VL[tv][th * 16]     = *(us8*)&ll[0];
            *(us8*)&VL[tv][th * 16 + 8] = *(us8*)&ll[8];
        }
        __syncthreads();
        // ---- MFMA: 16 tiles x 3 split terms ----
        bf16x8 ah[4], al[4];
        #pragma unroll
        for (int t = 0; t < 4; ++t) {
            ah[t] = *(const bf16x8*)&KpH[wr * 64 + t * 16 + fr][k8];
            al[t] = *(const bf16x8*)&KpL[wr * 64 + t * 16 + fr][k8];
        }
        #pragma unroll
        for (int u = 0; u < 4; ++u) {
            bf16x8 bh = *(const bf16x8*)&VH[wc * 64 + u * 16 + fr][k8];
            bf16x8 bl = *(const bf16x8*)&VL[wc * 64 + u * 16 + fr][k8];
            #pragma unroll
            for (int t = 0; t < 4; ++t) {
                acc[t][u] = __builtin_amdgcn_mfma_f32_16x16x32_bf16(ah[t], bh, acc[t][u], 0, 0, 0);
                acc[t][u] = __builtin_amdgcn_mfma_f32_16x16x32_bf16(ah[t], bl, acc[t][u], 0, 0, 0);
                acc[t][u] = __builtin_amdgcn_mfma_f32_16x16x32_bf16(al[t], bh, acc[t][u], 0, 0, 0);
            }
        }
    }

    // ---- store partial tile ----
    float* __restrict__ dKV = (ch == 0) ? KV : (ch == 1) ? P1 : (ch == 2) ? P2 : P3;
    #pragma unroll
    for (int t = 0; t < 4; ++t) {
        #pragma unroll
        for (int g = 0; g < 4; ++g) {
            const int row = wr * 64 + t * 16 + rg + g;
            const size_t base = ((size_t)b * MF + m0 + row) * DVV + v0 + wc * 64;
            #pragma unroll
            for (int u = 0; u < 4; ++u)
                dKV[base + u * 16 + fr] = acc[t][u][g];
        }
    }

    // ---- Ksum: exact-f32 per-thread partials -> LDS scratch -> reduce ----
    if (vt == 0) {
        __syncthreads();                       // bounce reads done
        float* scr = &Af[0][0];                // flat [8][128]
        *(float4*)&scr[(ln * 32 + lm4) * 4] = ks4;
        __syncthreads();
        if (tid < 128) {
            float s = 0.f;
            #pragma unroll
            for (int g = 0; g < 8; ++g) s += scr[g * 128 + tid];
            float* dst = (ch == 0) ? (Ksum + b * MF)
                                   : (KsumP + ((ch - 1) * NB + b) * MF);
            dst[m0 + tid] = s;
        }
    }
}

// ---------------------------------------------------------------------------
// Kernel 3b: fold the three partial buffers into KV / Ksum.  (unchanged)
// ---------------------------------------------------------------------------
__global__ __launch_bounds__(256) void kvreduce_kernel(
    float* __restrict__ KV, const float* __restrict__ P1,
    const float* __restrict__ P2, const float* __restrict__ P3,
    float* __restrict__ Ksum, const float* __restrict__ KsumP)
{
    const int idx = blockIdx.x * 256 + threadIdx.x;
    const int stride = gridDim.x * 256;
    const int TOT4 = NB * MF * DVV / 4;
    for (int i = idx; i < TOT4; i += stride) {
        float4 a  = ((const float4*)KV)[i];
        float4 p1 = ((const float4*)P1)[i];
        float4 p2 = ((const float4*)P2)[i];
        float4 p3 = ((const float4*)P3)[i];
        a.x += p1.x + p2.x + p3.x;
        a.y += p1.y + p2.y + p3.y;
        a.z += p1.z + p2.z + p3.z;
        a.w += p1.w + p2.w + p3.w;
        ((float4*)KV)[i] = a;
    }
    const int KS4 = NB * MF / 4;
    for (int i = idx; i < KS4; i += stride) {
        float4 a  = ((const float4*)Ksum)[i];
        float4 p1 = ((const float4*)KsumP)[i];
        float4 p2 = ((const float4*)KsumP)[i + KS4];
        float4 p3 = ((const float4*)KsumP)[i + 2 * KS4];
        a.x += p1.x + p2.x + p3.x;
        a.y += p1.y + p2.y + p3.y;
        a.z += p1.z + p2.z + p3.z;
        a.w += p1.w + p2.w + p3.w;
        ((float4*)Ksum)[i] = a;
    }
}

// ---------------------------------------------------------------------------
// Kernel 4: out = (Qp @ KV[b]) / (norm + eps) via bf16-split MFMA.
// (unchanged from r9 — validated)
// ---------------------------------------------------------------------------
__global__ __launch_bounds__(256) void out_kernel(
    const float* __restrict__ Qp, const float* __restrict__ KVm,
    const float* __restrict__ normv, float* __restrict__ out)
{
    __shared__ __align__(16) unsigned short Qh[128][40];
    __shared__ __align__(16) unsigned short Ql[128][40];
    __shared__ __align__(16) unsigned short Kh[128][40];
    __shared__ __align__(16) unsigned short Kl[128][40];
    __shared__ __align__(16) float Kf[32][132];
    __shared__ float nrmS[128];

    const int tid  = threadIdx.x;
    const int lane = tid & 63;
    const int w    = tid >> 6;
    const int wr   = w >> 1;
    const int wc   = w & 1;
    const int fr   = lane & 15;
    const int k8   = (lane >> 4) * 8;

    const int vt = blockIdx.x, rt = blockIdx.y, b = blockIdx.z;
    const int v0 = vt * 128;
    const int r0 = b * NPB + rt * 128;

    if (tid < 128) nrmS[tid] = normv[r0 + tid];

    const int qr  = tid >> 3;
    const int qm4 = tid & 7;
    const int km  = tid >> 5;
    const int kv4 = tid & 31;
    const int tv  = tid >> 1;
    const int th  = tid & 1;

    f32x4 acc[4][4] = {};

    for (int c = 0; c < 8; ++c) {
        const int mc = c * 32;
        __syncthreads();
        #pragma unroll
        for (int j = 0; j < 4; ++j) {
            float4 q = *(const float4*)&Qp[(size_t)(r0 + qr + 32 * j) * MF + mc + qm4 * 4];
            unsigned short h0, l0, h1, l1, h2, l2, h3, l3;
            bfsplit(q.x, h0, l0); bfsplit(q.y, h1, l1);
            bfsplit(q.z, h2, l2); bfsplit(q.w, h3, l3);
            us4 hv = {h0, h1, h2, h3};
            us4 lv = {l0, l1, l2, l3};
            *(us4*)&Qh[qr + 32 * j][qm4 * 4] = hv;
            *(us4*)&Ql[qr + 32 * j][qm4 * 4] = lv;

            *(float4*)&Kf[km + 8 * j][kv4 * 4] =
                *(const float4*)&KVm[((size_t)b * MF + mc + km + 8 * j) * DVV + v0 + kv4 * 4];
        }
        __syncthreads();
        {
            unsigned short hh[16], ll[16];
            #pragma unroll
            for (int s = 0; s < 16; ++s)
                bfsplit(Kf[th * 16 + s][tv], hh[s], ll[s]);
            *(us8*)&Kh[tv][th * 16]     = *(us8*)&hh[0];
            *(us8*)&Kh[tv][th * 16 + 8] = *(us8*)&hh[8];
            *(us8*)&Kl[tv][th * 16]     = *(us8*)&ll[0];
            *(us8*)&Kl[tv][th * 16 + 8] = *(us8*)&ll[8];
        }
        __syncthreads();
        bf16x8 ah[4], al[4];
        #pragma unroll
        for (int t = 0; t < 4; ++t) {
            ah[t] = *(const bf16x8*)&Qh[wr * 64 + t * 16 + fr][k8];
            al[t] = *(const bf16x8*)&Ql[wr * 64 + t * 16 + fr][k8];
        }
        #pragma unroll
        for (int u = 0; u < 4; ++u) {
            bf16x8 bh = *(const bf16x8*)&Kh[wc * 64 + u * 16 + fr][k8];
            bf16x8 bl = *(const bf16x8*)&Kl[wc * 64 + u * 16 + fr][k8];
            #pragma unroll
            for (int t = 0; t < 4; ++t) {
                acc[t][u] = __builtin_amdgcn_mfma_f32_16x16x32_bf16(ah[t], bh, acc[t][u], 0, 0, 0);
                acc[t][u] = __builtin_amdgcn_mfma_f32_16x16x32_bf16(ah[t], bl, acc[t][u], 0, 0, 0);
                acc[t][u] = __builtin_amdgcn_mfma_f32_16x16x32_bf16(al[t], bh, acc[t][u], 0, 0, 0);
            }
        }
    }

    const int rg = (lane >> 4) * 4;
    #pragma unroll
    for (int t = 0; t < 4; ++t) {
        #pragma unroll
        for (int g = 0; g < 4; ++g) {
            const int row = wr * 64 + t * 16 + rg + g;
            const float inv = 1.0f / (nrmS[row] + EPS_NORM);
            const size_t base = (size_t)(r0 + row) * DVV + v0 + wc * 64;
            #pragma unroll
            for (int u = 0; u < 4; ++u)
                out[base + u * 16 + fr] = acc[t][u][g] * inv;
        }
    }
}

// ---------------------------------------------------------------------------
extern "C" void kernel_launch(void* const* d_in, const int* in_sizes, int n_in,
                              void* d_out, int out_size, void* d_ws, size_t ws_size,
                              hipStream_t stream)
{
    const float* Q     = (const float*)d_in[0];
    const float* K     = (const float*)d_in[1];
    const float* V     = (const float*)d_in[2];
    const float* omega = (const float*)d_in[3];
    float* out = (float*)d_out;

    float* ws    = (float*)d_ws;
    float* Qp    = ws;                              // N*M  (holds P1,P2 during kv)
    float* A     = Qp    + (size_t)NTOT * MF;       // N*M   A' = exp(U-h-rmax)
    float* KV    = A     + (size_t)NTOT * MF;       // B*M*DV
    float* Ksum  = KV    + (size_t)NB * MF * DVV;   // B*M
    float* KsumP = Ksum  + (size_t)NB * MF;         // 3 * B*M
    float* rmaxA = KsumP + (size_t)3 * NB * MF;     // N
    float* sexp  = rmaxA + NTOT;                    // N
    float* normv = sexp  + NTOT;                    // N
    unsigned short* OmTh = (unsigned short*)(normv + NTOT);   // 256*128 us
    unsigned short* OmTl = OmTh + (size_t)MF * DQK;           // 256*128 us

    float* P1 = Qp;                                 // dead until phi_Q
    float* P2 = Qp + (size_t)NB * MF * DVV;
    float* P3 = out;                                // dead until out_kernel

    omsplit_kernel<<<DQK, 256, 0, stream>>>(omega, OmTh, OmTl);
    phi_kernel<false><<<NTOT / 64, 256, 0, stream>>>(K, OmTh, OmTl, (const float*)nullptr, A, rmaxA);
    segsexp_kernel<<<NB, 256, 0, stream>>>(rmaxA, sexp);
    kv_kernel<<<dim3(2, 2, NB * 4), 256, 0, stream>>>(A, V, sexp, KV, P1, P2, P3, Ksum, KsumP);
    kvreduce_kernel<<<2048, 256, 0, stream>>>(KV, P1, P2, P3, Ksum, KsumP);
    phi_kernel<true ><<<NTOT / 64, 256, 0, stream>>>(Q, OmTh, OmTl, Ksum, Qp, normv);
    out_kernel<<<dim3(2, 4, NB), 256, 0, stream>>>(Qp, KV, normv, out);
}

// Round 11
// 211.233 us; speedup vs baseline: 1.8040x; 1.0540x over previous
//
#include <hip/hip_runtime.h>
#include <math.h>

// Problem constants (fixed by the reference setup)
#define NTOT 32768
#define NB   64
#define NPB  512      // rows per segment
#define DQK  128
#define MF   256      // feature count m
#define DVV  256      // value dim

#define QK_SCALE   0.29730177875068026f   // 128^-0.25
#define INV_SQRT_M 0.0625f                // 1/sqrt(256)
#define EPS_PHI    1e-4f
#define EPS_NORM   1e-8f
#define EPS_ISM    (EPS_PHI * INV_SQRT_M)

typedef float f32x4  __attribute__((ext_vector_type(4)));
typedef short bf16x8 __attribute__((ext_vector_type(8)));
typedef unsigned short us4 __attribute__((ext_vector_type(4)));
typedef unsigned short us8 __attribute__((ext_vector_type(8)));

static __device__ __forceinline__ float red_max32(float v) {
    v = fmaxf(v, __shfl_xor(v, 1, 64));
    v = fmaxf(v, __shfl_xor(v, 2, 64));
    v = fmaxf(v, __shfl_xor(v, 4, 64));
    v = fmaxf(v, __shfl_xor(v, 8, 64));
    v = fmaxf(v, __shfl_xor(v, 16, 64));
    return v;
}
static __device__ __forceinline__ float red_sum16(float v) {
    v += __shfl_xor(v, 1, 64);
    v += __shfl_xor(v, 2, 64);
    v += __shfl_xor(v, 4, 64);
    v += __shfl_xor(v, 8, 64);
    return v;
}
static __device__ __forceinline__ float red_max16(float v) {
    v = fmaxf(v, __shfl_xor(v, 1, 64));
    v = fmaxf(v, __shfl_xor(v, 2, 64));
    v = fmaxf(v, __shfl_xor(v, 4, 64));
    v = fmaxf(v, __shfl_xor(v, 8, 64));
    return v;
}

// split f32 into bf16 hi + bf16 lo (RNE both): hi+lo ~ x to ~2^-17 rel.
static __device__ __forceinline__ void bfsplit(float x, unsigned short& h, unsigned short& l) {
    unsigned u = __float_as_uint(x);
    unsigned r = (u + 0x7fffu + ((u >> 16) & 1u)) & 0xffff0000u;
    h = (unsigned short)(r >> 16);
    float lo = x - __uint_as_float(r);
    unsigned v = __float_as_uint(lo);
    l = (unsigned short)((v + 0x7fffu + ((v >> 16) & 1u)) >> 16);
}

// ---------------------------------------------------------------------------
// Kernel 0 (r11): omega -> FRAGMENT-ORDERED bf16 hi/lo. For B-fragment of
// m-tile M16 (m = M16*16+fr), k-chunk c, lane l = fr + 16*(k8/8):
//   OmF[((M16*4 + c)*64 + l)*8 + s] = bf16(omega[c*32 + (l>>4)*8 + s][m]).
// A wave's B-frag load becomes ONE coalesced 1KB read (was 16x16B gather
// at stride 256B -> L2-latency-bound, r10's phi suspect cost).
// ---------------------------------------------------------------------------
__global__ __launch_bounds__(256) void omsplit_kernel(
    const float* __restrict__ omega,
    unsigned short* __restrict__ OmFh, unsigned short* __restrict__ OmFl)
{
    const int k = blockIdx.x;      // 0..127
    const int m = threadIdx.x;     // 0..255
    unsigned short h, l;
    bfsplit(omega[k * MF + m], h, l);
    const int M16 = m >> 4, fr = m & 15;
    const int c = k >> 5, kk = k & 31;
    const int lane = fr + 16 * (kk >> 3);
    const size_t idx = ((size_t)(M16 * 4 + c) * 64 + lane) * 8 + (kk & 7);
    OmFh[idx] = h;
    OmFl[idx] = l;
}

// ---------------------------------------------------------------------------
// Kernel 1 (MFMA): U = (X * d^-1/4) @ omega, 64 rows x 256 m per block.
// A = X staged f32 once, fragments bfsplit in regs. B = OmFh/OmFl read
// direct from global in fragment order (coalesced 1KB/wave, L2-resident).
//   IS_QUERY: outH/outL = bf16 split of Qp (out skips its Q bfsplit);
//             aux = norm (f32 q used before split).
//   else:     outF = exp(U-h-rowmax) f32; aux = rowmax.
// ---------------------------------------------------------------------------
template <bool IS_QUERY>
__global__ __launch_bounds__(256) void phi_kernel(
    const float* __restrict__ X,
    const unsigned short* __restrict__ OmFh, const unsigned short* __restrict__ OmFl,
    const float* __restrict__ Ksum,
    float* __restrict__ outF,
    unsigned short* __restrict__ outH, unsigned short* __restrict__ outL,
    float* __restrict__ aux)
{
    __shared__ __align__(16) float Xf[64][132];
    __shared__ float hS[64];
    __shared__ float mxW[4][64];
    __shared__ float npW[4][64];
    __shared__ float KsS[256];

    const int tid  = threadIdx.x;
    const int lane = tid & 63;
    const int w    = tid >> 6;        // wave = m-quadrant 0..3
    const int fr   = lane & 15;
    const int k8   = (lane >> 4) * 8;
    const int rg   = (lane >> 4) * 4;
    const int row0 = blockIdx.x * 64;

    if (IS_QUERY) KsS[tid] = Ksum[(row0 >> 9) * MF + tid];

    // ---- stage X (scaled, natural [row][k]) + exact f32 h partials ----
    float hp[8];
    {
        const float4* Xv = (const float4*)(X + (size_t)row0 * DQK);
        #pragma unroll
        for (int j = 0; j < 8; ++j) {
            int idx = tid + 256 * j;
            int r = idx >> 5, c4 = idx & 31;
            float4 v = Xv[idx];
            v.x *= QK_SCALE; v.y *= QK_SCALE; v.z *= QK_SCALE; v.w *= QK_SCALE;
            *(float4*)&Xf[r][c4 * 4] = v;
            hp[j] = v.x * v.x + v.y * v.y + v.z * v.z + v.w * v.w;
        }
    }
    __syncthreads();
    #pragma unroll
    for (int j = 0; j < 8; ++j) {
        hp[j] += __shfl_xor(hp[j], 1, 64);
        hp[j] += __shfl_xor(hp[j], 2, 64);
        hp[j] += __shfl_xor(hp[j], 4, 64);
        hp[j] += __shfl_xor(hp[j], 8, 64);
        hp[j] += __shfl_xor(hp[j], 16, 64);
    }
    if ((tid & 31) == 0) {
        #pragma unroll
        for (int j = 0; j < 8; ++j) hS[(tid >> 5) + 8 * j] = hp[j];
    }

    // ---- MFMA main loop (no barriers: Xf read-only, B from global) ----
    f32x4 acc[4][4] = {};    // [row-tile t][col-tile u]
    #pragma unroll
    for (int c = 0; c < 4; ++c) {
        bf16x8 ah[4], al[4];
        #pragma unroll
        for (int t = 0; t < 4; ++t) {
            float a[8];
            *(float4*)&a[0] = *(const float4*)&Xf[t * 16 + fr][c * 32 + k8];
            *(float4*)&a[4] = *(const float4*)&Xf[t * 16 + fr][c * 32 + k8 + 4];
            unsigned short hh[8], ll[8];
            #pragma unroll
            for (int s = 0; s < 8; ++s) bfsplit(a[s], hh[s], ll[s]);
            ah[t] = *(bf16x8*)&hh[0];
            al[t] = *(bf16x8*)&ll[0];
        }
        #pragma unroll
        for (int u = 0; u < 4; ++u) {
            const size_t ob = ((size_t)((w * 4 + u) * 4 + c) * 64 + lane) * 8;
            bf16x8 bh = *(const bf16x8*)&OmFh[ob];
            bf16x8 bl = *(const bf16x8*)&OmFl[ob];
            #pragma unroll
            for (int t = 0; t < 4; ++t) {
                acc[t][u] = __builtin_amdgcn_mfma_f32_16x16x32_bf16(ah[t], bh, acc[t][u], 0, 0, 0);
                acc[t][u] = __builtin_amdgcn_mfma_f32_16x16x32_bf16(ah[t], bl, acc[t][u], 0, 0, 0);
                acc[t][u] = __builtin_amdgcn_mfma_f32_16x16x32_bf16(al[t], bh, acc[t][u], 0, 0, 0);
            }
        }
    }

    // ---- rowmax: per-lane over u, reduce over fr lanes, cross-wave LDS ----
    #pragma unroll
    for (int t = 0; t < 4; ++t) {
        #pragma unroll
        for (int g = 0; g < 4; ++g) {
            float m0 = fmaxf(fmaxf(acc[t][0][g], acc[t][1][g]),
                             fmaxf(acc[t][2][g], acc[t][3][g]));
            m0 = red_max16(m0);
            if (fr == 0) mxW[w][t * 16 + rg + g] = m0;
        }
    }
    __syncthreads();

    // ---- epilogue ----
    #pragma unroll
    for (int t = 0; t < 4; ++t) {
        #pragma unroll
        for (int g = 0; g < 4; ++g) {
            const int row  = t * 16 + rg + g;
            const int grow = row0 + row;
            const float mxa = fmaxf(fmaxf(mxW[0][row], mxW[1][row]),
                                    fmaxf(mxW[2][row], mxW[3][row]));
            const float hm = 0.5f * hS[row] + mxa;
            if (IS_QUERY) {
                float np = 0.f;
                #pragma unroll
                for (int u = 0; u < 4; ++u) {
                    const int col = w * 64 + u * 16 + fr;
                    const float q = (__expf(acc[t][u][g] - hm) + EPS_PHI) * INV_SQRT_M;
                    unsigned short qh, ql;
                    bfsplit(q, qh, ql);
                    outH[(size_t)grow * MF + col] = qh;
                    outL[(size_t)grow * MF + col] = ql;
                    np = fmaf(q, KsS[col], np);
                }
                np = red_sum16(np);
                if (fr == 0) npW[w][row] = np;
            } else {
                #pragma unroll
                for (int u = 0; u < 4; ++u)
                    outF[(size_t)grow * MF + w * 64 + u * 16 + fr] = __expf(acc[t][u][g] - hm);
                if (w == 0 && fr == 0) aux[grow] = mxa;
            }
        }
    }
    if (IS_QUERY) {
        __syncthreads();
        if (w == 0 && fr == 0) {
            #pragma unroll
            for (int t = 0; t < 4; ++t)
                #pragma unroll
                for (int g = 0; g < 4; ++g) {
                    const int row = t * 16 + rg + g;
                    aux[row0 + row] = npW[0][row] + npW[1][row] + npW[2][row] + npW[3][row];
                }
        }
    }
}

// ---------------------------------------------------------------------------
// Kernel 2: sexp[n] = exp(rmax[n] - max_{segment} rmax)  (unchanged)
// ---------------------------------------------------------------------------
__global__ __launch_bounds__(256) void segsexp_kernel(
    const float* __restrict__ rmax, float* __restrict__ sexp)
{
    const int b = blockIdx.x, tid = threadIdx.x;
    const float r0 = rmax[b * NPB + tid];
    const float r1 = rmax[b * NPB + 256 + tid];
    float v = fmaxf(r0, r1);
    v = red_max32(v);
    v = fmaxf(v, __shfl_xor(v, 32, 64));
    __shared__ float red[4];
    if ((tid & 63) == 0) red[tid >> 6] = v;
    __syncthreads();
    const float smax = fmaxf(fmaxf(red[0], red[1]), fmaxf(red[2], red[3]));
    sexp[b * NPB + tid]       = __expf(r0 - smax);
    sexp[b * NPB + 256 + tid] = __expf(r1 - smax);
}

// ---------------------------------------------------------------------------
// Kernel 3 (MFMA, r11): KV partial over 256 n (2-way split -> half the
// partial traffic of r10's 4-way). grid (2,2,128) = 512 blocks = 2/CU
// (LDS 74.7KB). 8 chunks of 32 n. ch0 -> KV/Ksum; ch1 -> P1 (Qp region,
// dead until kvreduce) / KsumP. Same staging: f32 bounce -> transpose-read
// -> bfsplit -> bf16 [idx][n] tiles -> 16 tiles x 3 split terms MFMA.
// ---------------------------------------------------------------------------
__global__ __launch_bounds__(256) void kv_kernel(
    const float* __restrict__ A, const float* __restrict__ V,
    const float* __restrict__ sexp,
    float* __restrict__ KV, float* __restrict__ P1,
    float* __restrict__ Ksum, float* __restrict__ KsumP)
{
    __shared__ __align__(16) float Af[32][132];
    __shared__ __align__(16) float Vf[32][132];
    __shared__ __align__(16) unsigned short KpH[128][40];
    __shared__ __align__(16) unsigned short KpL[128][40];
    __shared__ __align__(16) unsigned short VH[128][40];
    __shared__ __align__(16) unsigned short VL[128][40];

    const int tid  = threadIdx.x;
    const int lane = tid & 63;
    const int w    = tid >> 6;
    const int wr   = w >> 1;          // m-quadrant
    const int wc   = w & 1;           // v-quadrant
    const int fr   = lane & 15;
    const int k8   = (lane >> 4) * 8;
    const int rg   = (lane >> 4) * 4;

    const int vt = blockIdx.x, mt = blockIdx.y;
    const int b  = blockIdx.z >> 1, ch = blockIdx.z & 1;
    const int m0 = mt * 128, v0 = vt * 128;
    const size_t n0 = (size_t)b * NPB + ch * 256;

    const int ln  = tid >> 5;     // staging n row (+8j)
    const int lm4 = tid & 31;     // staging float4 col
    const int tv  = tid >> 1;     // transpose-pass output row (m or v)
    const int th  = tid & 1;      // transpose-pass n-half

    f32x4 acc[4][4] = {};
    float4 ks4 = {0.f, 0.f, 0.f, 0.f};

    for (int c = 0; c < 8; ++c) {
        __syncthreads();
        // ---- phase A: global -> f32 bounces (+ exact Ksum partials) ----
        #pragma unroll
        for (int j = 0; j < 4; ++j) {
            const size_t n = n0 + c * 32 + ln + 8 * j;
            float4 a  = *(const float4*)&A[n * MF + m0 + lm4 * 4];
            float4 vv = *(const float4*)&V[n * DVV + v0 + lm4 * 4];
            const float s2 = sexp[n] * INV_SQRT_M;
            float4 e;
            e.x = fmaf(a.x, s2, EPS_ISM);
            e.y = fmaf(a.y, s2, EPS_ISM);
            e.z = fmaf(a.z, s2, EPS_ISM);
            e.w = fmaf(a.w, s2, EPS_ISM);
            ks4.x += e.x; ks4.y += e.y; ks4.z += e.z; ks4.w += e.w;
            *(float4*)&Af[ln + 8 * j][lm4 * 4] = e;
            *(float4*)&Vf[ln + 8 * j][lm4 * 4] = vv;
        }
        __syncthreads();
        // ---- phase B: transpose-read + bfsplit -> bf16 [idx][n] tiles ----
        {
            unsigned short hh[16], ll[16];
            #pragma unroll
            for (int s = 0; s < 16; ++s)
                bfsplit(Af[th * 16 + s][tv], hh[s], ll[s]);
            *(us8*)&KpH[tv][th * 16]     = *(us8*)&hh[0];
            *(us8*)&KpH[tv][th * 16 + 8] = *(us8*)&hh[8];
            *(us8*)&KpL[tv][th * 16]     = *(us8*)&ll[0];
            *(us8*)&KpL[tv][th * 16 + 8] = *(us8*)&ll[8];
            #pragma unroll
            for (int s = 0; s < 16; ++s)
                bfsplit(Vf[th * 16 + s][tv], hh[s], ll[s]);
            *(us8*)&VH[tv][th * 16]     = *(us8*)&hh[0];
            *(us8*)&VH[tv][th * 16 + 8] = *(us8*)&hh[8];
            *(us8*)&VL[tv][th * 16]     = *(us8*)&ll[0];
            *(us8*)&VL[tv][th * 16 + 8] = *(us8*)&ll[8];
        }
        __syncthreads();
        // ---- MFMA: 16 tiles x 3 split terms ----
        bf16x8 ah[4], al[4];
        #pragma unroll
        for (int t = 0; t < 4; ++t) {
            ah[t] = *(const bf16x8*)&KpH[wr * 64 + t * 16 + fr][k8];
            al[t] = *(const bf16x8*)&KpL[wr * 64 + t * 16 + fr][k8];
        }
        #pragma unroll
        for (int u = 0; u < 4; ++u) {
            bf16x8 bh = *(const bf16x8*)&VH[wc * 64 + u * 16 + fr][k8];
            bf16x8 bl = *(const bf16x8*)&VL[wc * 64 + u * 16 + fr][k8];
            #pragma unroll
            for (int t = 0; t < 4; ++t) {
                acc[t][u] = __builtin_amdgcn_mfma_f32_16x16x32_bf16(ah[t], bh, acc[t][u], 0, 0, 0);
                acc[t][u] = __builtin_amdgcn_mfma_f32_16x16x32_bf16(ah[t], bl, acc[t][u], 0, 0, 0);
                acc[t][u] = __builtin_amdgcn_mfma_f32_16x16x32_bf16(al[t], bh, acc[t][u], 0, 0, 0);
            }
        }
    }

    // ---- store partial tile ----
    float* __restrict__ dKV = ch ? P1 : KV;
    #pragma unroll
    for (int t = 0; t < 4; ++t) {
        #pragma unroll
        for (int g = 0; g < 4; ++g) {
            const int row = wr * 64 + t * 16 + rg + g;
            const size_t base = ((size_t)b * MF + m0 + row) * DVV + v0 + wc * 64;
            #pragma unroll
            for (int u = 0; u < 4; ++u)
                dKV[base + u * 16 + fr] = acc[t][u][g];
        }
    }

    // ---- Ksum: exact-f32 per-thread partials -> LDS scratch -> reduce ----
    if (vt == 0) {
        __syncthreads();                       // bounce reads done
        float* scr = &Af[0][0];                // flat [8][128]
        *(float4*)&scr[(ln * 32 + lm4) * 4] = ks4;
        __syncthreads();
        if (tid < 128) {
            float s = 0.f;
            #pragma unroll
            for (int g = 0; g < 8; ++g) s += scr[g * 128 + tid];
            (ch ? KsumP : Ksum)[b * MF + m0 + tid] = s;
        }
    }
}

// ---------------------------------------------------------------------------
// Kernel 3b: fold the single partial into KV / Ksum.
// ---------------------------------------------------------------------------
__global__ __launch_bounds__(256) void kvreduce_kernel(
    float* __restrict__ KV, const float* __restrict__ P1,
    float* __restrict__ Ksum, const float* __restrict__ KsumP)
{
    const int idx = blockIdx.x * 256 + threadIdx.x;
    const int stride = gridDim.x * 256;
    const int TOT4 = NB * MF * DVV / 4;
    for (int i = idx; i < TOT4; i += stride) {
        float4 a = ((const float4*)KV)[i];
        float4 p = ((const float4*)P1)[i];
        a.x += p.x; a.y += p.y; a.z += p.z; a.w += p.w;
        ((float4*)KV)[i] = a;
    }
    const int KS4 = NB * MF / 4;
    for (int i = idx; i < KS4; i += stride) {
        float4 a = ((const float4*)Ksum)[i];
        float4 p = ((const float4*)KsumP)[i];
        a.x += p.x; a.y += p.y; a.z += p.z; a.w += p.w;
        ((float4*)Ksum)[i] = a;
    }
}

// ---------------------------------------------------------------------------
// Kernel 4 (r11): out = (Qp @ KV[b]) / (norm + eps), bf16-split MFMA.
// Q arrives PRE-SPLIT (QpH/QpL from phi_Q) -> staging is a straight us4
// copy, no bfsplit pass for Q. KV: f32 bounce + transpose as before.
// ---------------------------------------------------------------------------
__global__ __launch_bounds__(256) void out_kernel(
    const unsigned short* __restrict__ QpH, const unsigned short* __restrict__ QpL,
    const float* __restrict__ KVm,
    const float* __restrict__ normv, float* __restrict__ out)
{
    __shared__ __align__(16) unsigned short Qh[128][40];
    __shared__ __align__(16) unsigned short Ql[128][40];
    __shared__ __align__(16) unsigned short Kh[128][40];
    __shared__ __align__(16) unsigned short Kl[128][40];
    __shared__ __align__(16) float Kf[32][132];
    __shared__ float nrmS[128];

    const int tid  = threadIdx.x;
    const int lane = tid & 63;
    const int w    = tid >> 6;
    const int wr   = w >> 1;
    const int wc   = w & 1;
    const int fr   = lane & 15;
    const int k8   = (lane >> 4) * 8;

    const int vt = blockIdx.x, rt = blockIdx.y, b = blockIdx.z;
    const int v0 = vt * 128;
    const int r0 = b * NPB + rt * 128;

    if (tid < 128) nrmS[tid] = normv[r0 + tid];

    const int qr  = tid >> 3;
    const int qm4 = tid & 7;
    const int km  = tid >> 5;
    const int kv4 = tid & 31;
    const int tv  = tid >> 1;
    const int th  = tid & 1;

    f32x4 acc[4][4] = {};

    for (int c = 0; c < 8; ++c) {
        const int mc = c * 32;
        __syncthreads();
        #pragma unroll
        for (int j = 0; j < 4; ++j) {
            const size_t qb = (size_t)(r0 + qr + 32 * j) * MF + mc + qm4 * 4;
            *(us4*)&Qh[qr + 32 * j][qm4 * 4] = *(const us4*)&QpH[qb];
            *(us4*)&Ql[qr + 32 * j][qm4 * 4] = *(const us4*)&QpL[qb];
            *(float4*)&Kf[km + 8 * j][kv4 * 4] =
                *(const float4*)&KVm[((size_t)b * MF + mc + km + 8 * j) * DVV + v0 + kv4 * 4];
        }
        __syncthreads();
        {
            unsigned short hh[16], ll[16];
            #pragma unroll
            for (int s = 0; s < 16; ++s)
                bfsplit(Kf[th * 16 + s][tv], hh[s], ll[s]);
            *(us8*)&Kh[tv][th * 16]     = *(us8*)&hh[0];
            *(us8*)&Kh[tv][th * 16 + 8] = *(us8*)&hh[8];
            *(us8*)&Kl[tv][th * 16]     = *(us8*)&ll[0];
            *(us8*)&Kl[tv][th * 16 + 8] = *(us8*)&ll[8];
        }
        __syncthreads();
        bf16x8 ah[4], al[4];
        #pragma unroll
        for (int t = 0; t < 4; ++t) {
            ah[t] = *(const bf16x8*)&Qh[wr * 64 + t * 16 + fr][k8];
            al[t] = *(const bf16x8*)&Ql[wr * 64 + t * 16 + fr][k8];
        }
        #pragma unroll
        for (int u = 0; u < 4; ++u) {
            bf16x8 bh = *(const bf16x8*)&Kh[wc * 64 + u * 16 + fr][k8];
            bf16x8 bl = *(const bf16x8*)&Kl[wc * 64 + u * 16 + fr][k8];
            #pragma unroll
            for (int t = 0; t < 4; ++t) {
                acc[t][u] = __builtin_amdgcn_mfma_f32_16x16x32_bf16(ah[t], bh, acc[t][u], 0, 0, 0);
                acc[t][u] = __builtin_amdgcn_mfma_f32_16x16x32_bf16(ah[t], bl, acc[t][u], 0, 0, 0);
                acc[t][u] = __builtin_amdgcn_mfma_f32_16x16x32_bf16(al[t], bh, acc[t][u], 0, 0, 0);
            }
        }
    }

    const int rg = (lane >> 4) * 4;
    #pragma unroll
    for (int t = 0; t < 4; ++t) {
        #pragma unroll
        for (int g = 0; g < 4; ++g) {
            const int row = wr * 64 + t * 16 + rg + g;
            const float inv = 1.0f / (nrmS[row] + EPS_NORM);
            const size_t base = (size_t)(r0 + row) * DVV + v0 + wc * 64;
            #pragma unroll
            for (int u = 0; u < 4; ++u)
                out[base + u * 16 + fr] = acc[t][u][g] * inv;
        }
    }
}

// ---------------------------------------------------------------------------
extern "C" void kernel_launch(void* const* d_in, const int* in_sizes, int n_in,
                              void* d_out, int out_size, void* d_ws, size_t ws_size,
                              hipStream_t stream)
{
    const float* Q     = (const float*)d_in[0];
    const float* K     = (const float*)d_in[1];
    const float* V     = (const float*)d_in[2];
    const float* omega = (const float*)d_in[3];
    float* out = (float*)d_out;

    float* ws    = (float*)d_ws;
    float* Qp    = ws;                              // N*M region: P1 during kv; QpH/QpL after phi_Q
    float* A     = Qp    + (size_t)NTOT * MF;       // N*M   A' = exp(U-h-rmax)
    float* KV    = A     + (size_t)NTOT * MF;       // B*M*DV
    float* Ksum  = KV    + (size_t)NB * MF * DVV;   // B*M
    float* KsumP = Ksum  + (size_t)NB * MF;         // B*M
    float* rmaxA = KsumP + (size_t)NB * MF;         // N
    float* sexp  = rmaxA + NTOT;                    // N
    float* normv = sexp  + NTOT;                    // N
    unsigned short* OmFh = (unsigned short*)(normv + NTOT);   // MF*DQK us
    unsigned short* OmFl = OmFh + (size_t)MF * DQK;           // MF*DQK us

    float* P1 = Qp;                                 // f32 partial; dead before phi_Q
    unsigned short* QpH = (unsigned short*)Qp;                // N*M us
    unsigned short* QpL = QpH + (size_t)NTOT * MF;            // N*M us

    omsplit_kernel<<<DQK, 256, 0, stream>>>(omega, OmFh, OmFl);
    phi_kernel<false><<<NTOT / 64, 256, 0, stream>>>(K, OmFh, OmFl, (const float*)nullptr,
                                                     A, (unsigned short*)nullptr, (unsigned short*)nullptr, rmaxA);
    segsexp_kernel<<<NB, 256, 0, stream>>>(rmaxA, sexp);
    kv_kernel<<<dim3(2, 2, NB * 2), 256, 0, stream>>>(A, V, sexp, KV, P1, Ksum, KsumP);
    kvreduce_kernel<<<2048, 256, 0, stream>>>(KV, P1, Ksum, KsumP);
    phi_kernel<true ><<<NTOT / 64, 256, 0, stream>>>(Q, OmFh, OmFl, Ksum,
                                                     (float*)nullptr, QpH, QpL, normv);
    out_kernel<<<dim3(2, 4, NB), 256, 0, stream>>>(QpH, QpL, KV, normv, out);
}